// Round 4
// baseline (6281.360 us; speedup 1.0000x reference)
//
#include <hip/hip_runtime.h>
#include <hip/hip_bf16.h>
#include <math.h>

#define NB 32      // batch
#define NN 500     // nodes
#define NF 32      // channels

typedef float f32x4 __attribute__((ext_vector_type(4)));
typedef short bf16x8 __attribute__((ext_vector_type(8)));

__device__ __forceinline__ float sigf(float x) { return 1.0f / (1.0f + __expf(-x)); }
// fast tanh: |err| ~1e-7, no overflow (e in (0,1])
__device__ __forceinline__ float tanhf_fast(float x) {
  float e = __expf(-2.0f * fabsf(x));
  float r = (1.0f - e) / (1.0f + e);
  return copysignf(r, x);
}

__device__ __forceinline__ unsigned short bf16rne(float x) {
  unsigned int u = __float_as_uint(x);
  unsigned int r = u + 0x7FFFu + ((u >> 16) & 1u);
  return (unsigned short)(r >> 16);
}
__device__ __forceinline__ float bfval(unsigned short h) {
  return __uint_as_float((unsigned int)h << 16);
}

__global__ void k_zero(float* p, int n) {
  int i = blockIdx.x * 256 + threadIdx.x;
  if (i < n) p[i] = 0.f;
}

// h[b,c,n,t] = b_start[c] + sum_ci w_start[c,ci]*padded_x[b,ci,n,t]; pad 7 zeros at front (19)
__global__ void k_start(const float* x, const float* w, const float* bias, float* h) {
  int idx = blockIdx.x * 256 + threadIdx.x;
  const int total = NB * NF * NN * 19;
  if (idx >= total) return;
  int t = idx % 19;
  int n = (idx / 19) % NN;
  int c = (idx / (19 * NN)) % NF;
  int b = idx / (19 * NN * NF);
  float v = bias[c];
  if (t >= 7) {
    int tx = t - 7;
    v += w[c * 2 + 0] * x[((size_t)(b * 2 + 0) * NN + n) * 12 + tx];
    v += w[c * 2 + 1] * x[((size_t)(b * 2 + 1) * NN + n) * 12 + tx];
  }
  h[idx] = v;
}

// skip0[b,c,n] = b_sk0[c] + sum_{ci,k>=7} w_sk0[c,ci,k]*x[b,ci,n,k-7]
__global__ void k_skip0(const float* x, const float* w, const float* bias, float* s0) {
  int idx = blockIdx.x * 256 + threadIdx.x;
  const int total = NB * 64 * NN;
  if (idx >= total) return;
  int n = idx % NN;
  int c = (idx / NN) % 64;
  int b = idx / (NN * 64);
  float v = bias[c];
  for (int ci = 0; ci < 2; ci++)
    for (int k = 7; k < 19; k++)
      v += w[(c * 2 + ci) * 19 + k] * x[((size_t)(b * 2 + ci) * NN + n) * 12 + (k - 7)];
  s0[idx] = v;
}

// ---- fused gated-TCN + fc; gtu_seg generalized over LDS strides (TS=time, CS=channel) ----
template<int K, int L, int TS, int CS, int TCAT, int TO>
__device__ __forceinline__ void gtu_seg(const float* __restrict__ wseg,
                                        const float* __restrict__ bg,
                                        const float* __restrict__ hbase,
                                        const float* __restrict__ fw,
                                        float (&oacc)[TO], int c, int tbase) {
  float y0[L], y1[L];
#pragma unroll
  for (int t = 0; t < L; t++) { y0[t] = 0.f; y1[t] = 0.f; }
#pragma unroll 2
  for (int ci = 0; ci < NF; ci++) {
    float hrow[L + K - 1];
    if constexpr (TS == 1) {
      constexpr int HL = L + K - 1;
#pragma unroll
      for (int t4 = 0; t4 + 4 <= HL; t4 += 4)
        *(float4*)&hrow[t4] = *(const float4*)&hbase[ci * CS + t4];
#pragma unroll
      for (int t = HL & ~3; t < HL; t++) hrow[t] = hbase[ci * CS + t];
    } else {
#pragma unroll
      for (int t = 0; t < L + K - 1; t++) hrow[t] = hbase[ci * CS + t * TS];
    }
    float w0[K], w1[K];
#pragma unroll
    for (int j = 0; j < K; j++) {
      w0[j] = wseg[(c * NF + ci) * K + j];
      w1[j] = wseg[((c + 32) * NF + ci) * K + j];
    }
#pragma unroll
    for (int t = 0; t < L; t++)
#pragma unroll
      for (int j = 0; j < K; j++) {
        y0[t] += w0[j] * hrow[t + j];
        y1[t] += w1[j] * hrow[t + j];
      }
  }
  float b0 = bg[c], b1 = bg[c + 32];
#pragma unroll
  for (int t = 0; t < L; t++) {
    float tcv = tanhf_fast(y0[t] + b0) * sigf(y1[t] + b1);
#pragma unroll
    for (int o = 0; o < TO; o++) oacc[o] += tcv * fw[o * TCAT + tbase + t];
  }
}

// standard-layout input h[b,c,n,t]
template<int TI, int TO>
__global__ __launch_bounds__(256, 4) void k_gtufc_t(
    const float* __restrict__ h,
    const float* __restrict__ wg3, const float* __restrict__ bg3,
    const float* __restrict__ wg5, const float* __restrict__ bg5,
    const float* __restrict__ wg7, const float* __restrict__ bg7,
    const float* __restrict__ fw, const float* __restrict__ fb,
    const float* __restrict__ res, float* __restrict__ out) {
  constexpr int TCAT = 3 * TI - 12;
  constexpr int TP = (TI + 3) & ~3;
  constexpr int OFF = TI - TO;
  const int b = blockIdx.y;
  const int n0 = blockIdx.x * 8;
  const int tid = threadIdx.x;
  const int c = tid & 31, nn = tid >> 5;
  const int n = n0 + nn;
  __shared__ float hs[8 * NF * TP];
  for (int l = tid; l < 8 * NF * TP; l += 256) {
    int t = l % TP;
    int ci = (l / TP) % NF;
    int n2 = l / (TP * NF);
    int gn = n0 + n2;
    hs[l] = (t < TI && gn < NN) ? h[((size_t)(b * NF + ci) * NN + gn) * TI + t] : 0.f;
  }
  __syncthreads();
  const float* hbase = hs + nn * NF * TP;
  float oacc[TO];
#pragma unroll
  for (int o = 0; o < TO; o++) oacc[o] = 0.f;
  gtu_seg<3, TI - 2, 1, TP, TCAT, TO>(wg3, bg3, hbase, fw, oacc, c, 0);
  gtu_seg<5, TI - 4, 1, TP, TCAT, TO>(wg5, bg5, hbase, fw, oacc, c, TI - 2);
  gtu_seg<7, TI - 6, 1, TP, TCAT, TO>(wg7, bg7, hbase, fw, oacc, c, 2 * TI - 6);
  if (n < NN) {
    size_t base = (size_t)(b * NF + c) * NN + n;
#pragma unroll
    for (int o = 0; o < TO; o++) {
      float v = fmaxf(hbase[c * TP + OFF + o] + oacc[o] + fb[o], 0.f);
      if (res) v += res[base * TI + OFF + o];
      out[base * TO + o] = v;
    }
  }
}

// t-major input hX[b][n][t*NF+f] (cheb output layout); output standard layout
template<int TI, int TO>
__global__ __launch_bounds__(256, 4) void k_gtufc_x(
    const float* __restrict__ hX,
    const float* __restrict__ wg3, const float* __restrict__ bg3,
    const float* __restrict__ wg5, const float* __restrict__ bg5,
    const float* __restrict__ wg7, const float* __restrict__ bg7,
    const float* __restrict__ fw, const float* __restrict__ fb,
    const float* __restrict__ res, float* __restrict__ out) {
  constexpr int TCAT = 3 * TI - 12;
  constexpr int NFT = NF * TI;
  constexpr int OFF = TI - TO;
  const int b = blockIdx.y;
  const int n0 = blockIdx.x * 8;
  const int tid = threadIdx.x;
  const int c = tid & 31, nn = tid >> 5;
  const int n = n0 + nn;
  __shared__ float hs[8 * NFT];
  for (int l = tid; l < 8 * NFT; l += 256) {
    int n2 = l / NFT, l2 = l % NFT;
    int gn = n0 + n2;
    hs[l] = (gn < NN) ? hX[(size_t)(b * NN + gn) * NFT + l2] : 0.f;
  }
  __syncthreads();
  const float* hbase = hs + nn * NFT;
  float oacc[TO];
#pragma unroll
  for (int o = 0; o < TO; o++) oacc[o] = 0.f;
  gtu_seg<3, TI - 2, NF, 1, TCAT, TO>(wg3, bg3, hbase, fw, oacc, c, 0);
  gtu_seg<5, TI - 4, NF, 1, TCAT, TO>(wg5, bg5, hbase, fw, oacc, c, TI - 2);
  gtu_seg<7, TI - 6, NF, 1, TCAT, TO>(wg7, bg7, hbase, fw, oacc, c, 2 * TI - 6);
  if (n < NN) {
    size_t base = (size_t)(b * NF + c) * NN + n;
#pragma unroll
    for (int o = 0; o < TO; o++) {
      float v = fmaxf(hbase[(OFF + o) * NF + c] + oacc[o] + fb[o], 0.f);
      if (res) v += res[base * TI + OFF + o];
      out[base * TO + o] = v;
    }
  }
}

// ---- skip conv, LDS h staging, weights in registers, K unrolled ----
template<int TI, int K>
__global__ __launch_bounds__(256, 4) void k_skipconv_t(
    const float* __restrict__ h, const float* __restrict__ w,
    const float* __restrict__ bias, const float* __restrict__ prev, int prevT,
    float* __restrict__ out) {
  constexpr int TP = (TI + 3) & ~3;
  const int b = blockIdx.y, n0 = blockIdx.x * 8, tid = threadIdx.x;
  __shared__ float hs[8 * NF * TP];
  for (int l = tid; l < 8 * NF * TP; l += 256) {
    int t = l % TP;
    int ci = (l / TP) % NF;
    int n2 = l / (TP * NF);
    int gn = n0 + n2;
    hs[l] = (t < TI && gn < NN) ? h[((size_t)(b * NF + ci) * NN + gn) * TI + t] : 0.f;
  }
  __syncthreads();
  const int c = tid & 63, ng = tid >> 6;
  float bv = bias[c];
  float o[2][7];
#pragma unroll
  for (int q = 0; q < 2; q++)
#pragma unroll
    for (int t = 0; t < 7; t++) o[q][t] = bv;
  for (int ci = 0; ci < NF; ci++) {
    float wv[K];
#pragma unroll
    for (int j = 0; j < K; j++) wv[j] = w[(c * NF + ci) * K + j];
#pragma unroll
    for (int q = 0; q < 2; q++) {
      const float* hp = hs + ((ng + q * 4) * NF + ci) * TP;
#pragma unroll
      for (int t = 0; t < 7; t++) {
        float s = 0.f;
#pragma unroll
        for (int j = 0; j < K; j++) s += wv[j] * hp[t + j];
        o[q][t] += s;
      }
    }
  }
#pragma unroll
  for (int q = 0; q < 2; q++) {
    int n = n0 + ng + q * 4;
    if (n < NN) {
      size_t base = (size_t)(b * 64 + c) * NN + n;
#pragma unroll
      for (int t = 0; t < 7; t++) {
        float pv = (prevT == 1) ? prev[base] : prev[base * 7 + t];
        out[base * 7 + t] = o[q][t] + pv;
      }
    }
  }
}

// ---- temporal attention ----
// lhs1[b][t][f] += sum_{n in chunk} u1[n]*h[b,f,n,t]; chunked LDS staging + atomics.
// grid (20 chunks of 25 n, NB); out must be zeroed first.
__global__ __launch_bounds__(256) void k_ta_lhs1b(const float* __restrict__ h,
                                                  const float* __restrict__ u1,
                                                  float* __restrict__ out, int T) {
  const int ch = blockIdx.x, b = blockIdx.y;
  const int n0 = ch * 25;
  const int tid = threadIdx.x;
  __shared__ float hs[25 * NF * 19];  // [n][f][t]
  const int tot = 25 * NF * T;
  for (int l = tid; l < tot; l += 256) {
    int t = l % T;
    int f = (l / T) % NF;
    int n2 = l / (T * NF);
    hs[(n2 * NF + f) * T + t] = h[((size_t)(b * NF + f) * NN + n0 + n2) * T + t];
  }
  __syncthreads();
  for (int l2 = tid; l2 < NF * T; l2 += 256) {
    int f = l2 / T, t = l2 % T;
    float acc = 0.f;
#pragma unroll 5
    for (int n2 = 0; n2 < 25; n2++)
      acc += hs[(n2 * NF + f) * T + t] * u1[n0 + n2];
    atomicAdd(&out[(b * T + t) * NF + f], acc);
  }
}
__global__ void k_ta_lhs(const float* l1, const float* u2, float* out, int T) {
  int total = NB * T * NN;
  int idx = blockIdx.x * 256 + threadIdx.x;
  if (idx >= total) return;
  int n = idx % NN;
  int t = (idx / NN) % T;
  int b = idx / (NN * T);
  float acc = 0.f;
  for (int f = 0; f < NF; f++) acc += l1[(b * T + t) * NF + f] * u2[f * NN + n];
  out[idx] = acc;  // (b,t,n)
}
__global__ void k_ta_rhs(const float* h, const float* u3, float* out, int T) {
  int total = NB * NN * T;
  int idx = blockIdx.x * 256 + threadIdx.x;
  if (idx >= total) return;
  int t = idx % T;
  int n = (idx / T) % NN;
  int b = idx / (T * NN);
  float acc = 0.f;
  for (int f = 0; f < NF; f++) acc += u3[f] * h[((size_t)(b * NF + f) * NN + n) * T + t];
  out[idx] = acc;  // (b,n,t)
}
// e0[b][t][m] = sigf(sum_n lhs[b,t,n]*rhs[b,n,m] + be[t,m]); block per (t,b)
__global__ __launch_bounds__(256) void k_ta_e0(const float* __restrict__ lhs,
                                               const float* __restrict__ rhs,
                                               const float* __restrict__ be,
                                               float* __restrict__ e0g, int T) {
  const int t = blockIdx.x, b = blockIdx.y, tid = threadIdx.x;
  const float* lp = lhs + ((size_t)b * T + t) * NN;
  const float* rp = rhs + (size_t)b * NN * T;
  float acc[19];
#pragma unroll
  for (int m = 0; m < 19; m++) acc[m] = 0.f;
  for (int n = tid; n < NN; n += 256) {
    float lv = lp[n];
    const float* rr = rp + (size_t)n * T;
    for (int m = 0; m < T; m++) acc[m] += lv * rr[m];
  }
  __shared__ float red[256 * 20];
  for (int m = 0; m < T; m++) red[tid * 20 + m] = acc[m];
  __syncthreads();
  for (int s = 128; s > 0; s >>= 1) {
    if (tid < s)
      for (int m = 0; m < T; m++) red[tid * 20 + m] += red[(tid + s) * 20 + m];
    __syncthreads();
  }
  if (tid < T)
    e0g[((size_t)b * T + t) * T + tid] = sigf(red[tid] + be[t * T + tid]);
}
// e1 = ve@e0; e = softmax over t. one block per b.
__global__ __launch_bounds__(256) void k_ta_att2(const float* __restrict__ e0g,
                                                 const float* __restrict__ ve,
                                                 float* __restrict__ e, int T) {
  int b = blockIdx.x, tid = threadIdx.x;
  __shared__ float e0[19 * 19];
  __shared__ float e1[19 * 19];
  int TT = T * T;
  for (int l = tid; l < TT; l += 256) e0[l] = e0g[(size_t)b * TT + l];
  __syncthreads();
  for (int l = tid; l < TT; l += 256) {
    int t = l / T, m = l % T;
    float acc = 0.f;
    for (int j = 0; j < T; j++) acc += ve[t * T + j] * e0[j * T + m];
    e1[l] = acc;
  }
  __syncthreads();
  if (tid < T) {
    int m = tid;
    float mx = -1e30f;
    for (int t = 0; t < T; t++) mx = fmaxf(mx, e1[t * T + m]);
    float s = 0.f;
    for (int t = 0; t < T; t++) s += __expf(e1[t * T + m] - mx);
    float inv = 1.f / s;
    for (int t = 0; t < T; t++)
      e[((size_t)b * T + t) * T + m] = __expf(e1[t * T + m] - mx) * inv;
  }
}
// xt[b,f,n,t] = sum_j e[b,t,j] * h[b,f,n,j]
__global__ void k_xtat(const float* e, const float* h, float* xt, int T) {
  int total = NB * NF * NN * T;
  int idx = blockIdx.x * 256 + threadIdx.x;
  if (idx >= total) return;
  int t = idx % T;
  int n = (idx / T) % NN;
  int f = (idx / (T * NN)) % NF;
  int b = idx / (T * NN * NF);
  const float* hp = h + ((size_t)(b * NF + f) * NN + n) * T;
  float acc = 0.f;
  for (int j = 0; j < T; j++) acc += e[(b * T + t) * T + j] * hp[j];
  xt[idx] = acc;
}

// ---- spatial attention ----
__global__ void k_sa_lhs1(const float* xt, const float* w1, float* out, int T) {
  int total = NB * NN * NF;
  int idx = blockIdx.x * 256 + threadIdx.x;
  if (idx >= total) return;
  int f = idx % NF;
  int n = (idx / NF) % NN;
  int b = idx / (NF * NN);
  const float* xp = xt + ((size_t)(b * NF + f) * NN + n) * T;
  float acc = 0.f;
  for (int t = 0; t < T; t++) acc += xp[t] * w1[t];
  out[(b * NN + n) * NF + f] = acc;
}
__global__ void k_sa_lhs(const float* l1, const float* w2, float* out, int T) {
  int total = NB * NN * T;
  int idx = blockIdx.x * 256 + threadIdx.x;
  if (idx >= total) return;
  int t = idx % T;
  int n = (idx / T) % NN;
  int b = idx / (T * NN);
  float acc = 0.f;
  for (int f = 0; f < NF; f++) acc += l1[(b * NN + n) * NF + f] * w2[f * T + t];
  out[idx] = acc;  // (b,n,t)
}
__global__ void k_sa_rhs(const float* xt, const float* w3, float* out, int T) {
  int total = NB * T * NN;
  int idx = blockIdx.x * 256 + threadIdx.x;
  if (idx >= total) return;
  int n = idx % NN;
  int t = (idx / NN) % T;
  int b = idx / (NN * T);
  float acc = 0.f;
  for (int f = 0; f < NF; f++) acc += w3[f] * xt[((size_t)(b * NF + f) * NN + n) * T + t];
  out[idx] = acc;  // (b,t,n)
}
__global__ void k_sa_prod(const float* lhs, const float* rhs, const float* bs, float* s0, int T) {
  int total = NB * NN * NN;
  int idx = blockIdx.x * 256 + threadIdx.x;
  if (idx >= total) return;
  int m = idx % NN;
  int n = (idx / NN) % NN;
  int b = idx / (NN * NN);
  float acc = 0.f;
  for (int t = 0; t < T; t++)
    acc += lhs[((size_t)b * NN + n) * T + t] * rhs[((size_t)b * T + t) * NN + m];
  s0[idx] = sigf(acc + bs[(size_t)n * NN + m]);
}

// 500x500 transpose (for vs)
__global__ __launch_bounds__(256) void k_transpose(const float* in, float* outT) {
  __shared__ float tile[32][33];
  int x0 = blockIdx.x * 32, y0 = blockIdx.y * 32;
  int tx = threadIdx.x & 31, ty8 = threadIdx.x >> 5;
  for (int yy = ty8; yy < 32; yy += 8) {
    int x = x0 + tx, y = y0 + yy;
    tile[yy][tx] = (x < NN && y < NN) ? in[(size_t)y * NN + x] : 0.f;
  }
  __syncthreads();
  for (int yy = ty8; yy < 32; yy += 8) {
    int x = y0 + tx, y = x0 + yy;
    if (x < NN && y < NN) outT[(size_t)y * NN + x] = tile[tx][yy];
  }
}

// s1T[b,c,r] = (vs @ s0[b])[r,c] — 64x128 tile, double-buffered, float4 everywhere
__global__ __launch_bounds__(256) void k_gemm_vs(const float* __restrict__ vsT,
                                                 const float* __restrict__ s0,
                                                 float* __restrict__ s1t) {
  const int b = blockIdx.z;
  const int row0 = blockIdx.y * 64, col0 = blockIdx.x * 128;
  const int tid = threadIdx.x;
  const int tx = tid & 15, ty = tid >> 4;
  __shared__ float smem[6400];      // 2 x (As 16x68 + Bs 16x132)
  float acc[4][8] = {};
  const float* S0 = s0 + (size_t)b * NN * NN;
  const int nch = (NN + 15) / 16;
  float4 pa, pb0, pb1;
  auto loadregs = [&](int k0) {
    {
      int rq = tid & 15, kk = tid >> 4;
      int gk = k0 + kk, gi = row0 + rq * 4;
      float4 v = {0.f, 0.f, 0.f, 0.f};
      if (gk < NN && gi < NN) v = *(const float4*)&vsT[(size_t)gk * NN + gi];
      pa = v;
    }
#pragma unroll
    for (int it = 0; it < 2; it++) {
      int l = tid + it * 256;
      int q = l & 31, kk = l >> 5;
      int gk = k0 + kk, gc = col0 + q * 4;
      float4 v = {0.f, 0.f, 0.f, 0.f};
      if (gk < NN && gc < NN) v = *(const float4*)&S0[(size_t)gk * NN + gc];
      if (it == 0) pb0 = v; else pb1 = v;
    }
  };
  auto writebuf = [&](int buf) {
    float* As = smem + buf * 3200;
    float* Bs = As + 1088;
    {
      int rq = tid & 15, kk = tid >> 4;
      *(float4*)&As[kk * 68 + rq * 4] = pa;
    }
#pragma unroll
    for (int it = 0; it < 2; it++) {
      int l = tid + it * 256;
      int q = l & 31, kk = l >> 5;
      *(float4*)&Bs[kk * 132 + q * 4] = (it == 0) ? pb0 : pb1;
    }
  };
  loadregs(0);
  writebuf(0);
  for (int ch = 0; ch < nch; ch++) {
    int cur = ch & 1;
    if (ch + 1 < nch) loadregs((ch + 1) * 16);
    __syncthreads();
    const float* As = smem + cur * 3200;
    const float* Bs = As + 1088;
#pragma unroll
    for (int kk = 0; kk < 16; kk++) {
      float4 a4 = *(const float4*)&As[kk * 68 + ty * 4];
      float4 b0 = *(const float4*)&Bs[kk * 132 + tx * 4];
      float4 b1 = *(const float4*)&Bs[kk * 132 + 64 + tx * 4];
      float a[4] = {a4.x, a4.y, a4.z, a4.w};
      float bb[8] = {b0.x, b0.y, b0.z, b0.w, b1.x, b1.y, b1.z, b1.w};
#pragma unroll
      for (int i = 0; i < 4; i++)
#pragma unroll
        for (int j = 0; j < 8; j++) acc[i][j] += a[i] * bb[j];
    }
    if (ch + 1 < nch) writebuf((ch + 1) & 1);
  }
  float* S1 = s1t + (size_t)b * NN * NN;
  int gi0 = row0 + ty * 4;
  if (gi0 < NN) {  // NN%4==0 so gi0<NN implies gi0+3<NN
#pragma unroll
    for (int j = 0; j < 8; j++) {
      int gc = col0 + (j < 4 ? tx * 4 + j : 64 + tx * 4 + (j - 4));
      if (gc < NN) {
        float4 v = {acc[0][j], acc[1][j], acc[2][j], acc[3][j]};
        *(float4*)&S1[(size_t)gc * NN + gi0] = v;
      }
    }
  }
}

// chebT[k,n,m] = cheb[k,m,n]
__global__ void k_chebT(const float* cheb, float* ct) {
  int total = 3 * NN * NN;
  int idx = blockIdx.x * 256 + threadIdx.x;
  if (idx >= total) return;
  int m = idx % NN;
  int n = (idx / NN) % NN;
  int k = idx / (NN * NN);
  ct[idx] = cheb[((size_t)k * NN + m) * NN + n];
}

// thetaT[k][f2][f] = theta[k][f][f2] (for vector-load access in k_prepY2)
__global__ void k_thetaT(const float* theta, float* tht) {
  int idx = blockIdx.x * 256 + threadIdx.x;
  if (idx >= 3 * NF * NF) return;
  int f = idx & 31, f2 = (idx >> 5) & 31, k = idx >> 10;
  tht[idx] = theta[(k * NF + f) * NF + f2];
}

// ==== cheb path: in-place softmax, on-the-fly A, full-batch-group launches ====

// softmax in place over each row of s1t (probs stay in bufC); extracts sd[b][n] = p[n,n]
__global__ __launch_bounds__(256) void k_smax_ip(float* __restrict__ s1t,
                                                 float* __restrict__ sd) {
  const int n = blockIdx.x, b = blockIdx.y, tid = threadIdx.x;
  float* S = s1t + ((size_t)b * NN + n) * NN;
  __shared__ float red[256];
  float mx = -1e30f;
  for (int i = tid; i < NN; i += 256) mx = fmaxf(mx, S[i]);
  red[tid] = mx;
  __syncthreads();
  for (int s = 128; s > 0; s >>= 1) {
    if (tid < s) red[tid] = fmaxf(red[tid], red[tid + s]);
    __syncthreads();
  }
  mx = red[0];
  __syncthreads();
  float sum = 0.f;
  for (int i = tid; i < NN; i += 256) sum += __expf(S[i] - mx);
  red[tid] = sum;
  __syncthreads();
  for (int s = 128; s > 0; s >>= 1) {
    if (tid < s) red[tid] += red[tid + s];
    __syncthreads();
  }
  float inv = 1.f / red[0];
  for (int i = tid; i < NN; i += 256) {
    float v = __expf(S[i] - mx) * inv;
    S[i] = v;
    if (i == n) sd[(size_t)b * NN + n] = v;
  }
}

// Y_k = h . theta_k. Y1/Y2 -> bf16 hi/lo B planes [bl][2][NFT][1024]; Y0 -> fp32.
__global__ __launch_bounds__(256) void k_prepY2(const float* __restrict__ h,
                                                const float* __restrict__ tht, int T, int b0,
                                                unsigned short* __restrict__ Bb,
                                                float* __restrict__ Y0) {
  const int t = blockIdx.x, bl = blockIdx.y, b = b0 + bl;
  const int NFT = NF * T;
  const int tid = threadIdx.x;
  __shared__ float hs[NF * NN];  // [f][m]
  for (int l = tid; l < NF * NN; l += 256) {
    int m = l % NN, f = l / NN;
    hs[l] = h[((size_t)(b * NF + f) * NN + m) * T + t];
  }
  __syncthreads();
  const int lane = tid & 63;
  const int w = tid >> 6;
  for (int m = lane; m < 512; m += 64) {
    float hv[NF];
    const bool valid = m < NN;
#pragma unroll
    for (int f = 0; f < NF; f++) hv[f] = valid ? hs[f * NN + m] : 0.f;
    for (int f2q = 0; f2q < 8; f2q++) {
      const int f2 = f2q * 4 + w;
      float a0 = 0.f, a1 = 0.f, a2 = 0.f;
#pragma unroll
      for (int fq = 0; fq < 8; fq++) {
        float4 t0 = *(const float4*)&tht[(0 * NF + f2) * NF + fq * 4];
        float4 t1 = *(const float4*)&tht[(1 * NF + f2) * NF + fq * 4];
        float4 t2 = *(const float4*)&tht[(2 * NF + f2) * NF + fq * 4];
        a0 += hv[fq * 4 + 0] * t0.x + hv[fq * 4 + 1] * t0.y + hv[fq * 4 + 2] * t0.z + hv[fq * 4 + 3] * t0.w;
        a1 += hv[fq * 4 + 0] * t1.x + hv[fq * 4 + 1] * t1.y + hv[fq * 4 + 2] * t1.z + hv[fq * 4 + 3] * t1.w;
        a2 += hv[fq * 4 + 0] * t2.x + hv[fq * 4 + 1] * t2.y + hv[fq * 4 + 2] * t2.z + hv[fq * 4 + 3] * t2.w;
      }
      const int c = t * NF + f2;
      unsigned short* Bhi = Bb + (size_t)bl * NFT * 2048 + (size_t)c * 1024;
      unsigned short* Blo = Bhi + (size_t)NFT * 1024;
      if (valid) Y0[((size_t)bl * NFT + c) * NN + m] = a0;
      unsigned short h1 = bf16rne(a1);
      Bhi[m] = h1;
      Blo[m] = bf16rne(a1 - bfval(h1));
      unsigned short h2 = bf16rne(a2);
      Bhi[512 + m] = h2;
      Blo[512 + m] = bf16rne(a2 - bfval(h2));
    }
  }
}

// C[n,c] = sum_m' A[n,m'] * B[m',c] via mfma_f32_16x16x32_bf16, bf16x3 (hi/lo split).
__global__ __launch_bounds__(256) void k_cheb_mfma2(
    const unsigned short* __restrict__ Bb, const float* __restrict__ probs,
    const float* __restrict__ ct, const float* __restrict__ Y0,
    const float* __restrict__ sd, int b0, int NFT, float* __restrict__ outX) {
  const int bl = blockIdx.z, b = b0 + bl;
  const int n0 = blockIdx.y * 128;
  const int c0 = blockIdx.x * 128;
  const int tid = threadIdx.x, lane = tid & 63;
  const int wm = (tid >> 7) & 1, wn = (tid >> 6) & 1;
  __shared__ char lds[65536];  // 2 x 32KB: Ahi 8K | Alo 8K | Bhi 8K | Blo 8K
  // ---- staging roles ----
  const int ar = tid >> 1, ahf = tid & 1;          // A: row 0..127, 16-el half
  const int aw0 = ar * 64 + ((((ahf << 1) | 0) ^ (ar & 3)) << 4);
  const int aw1 = ar * 64 + ((((ahf << 1) | 1) ^ (ar & 3)) << 4);
  const int br = tid >> 1, bp = tid & 1;           // B: row 0..127, plane hi/lo
  int brr = c0 + br;
  if (brr >= NFT) brr = 0;                         // clamp: lands in write-masked cols
  const unsigned short* gB = Bb + (size_t)bl * NFT * 2048 + (size_t)bp * NFT * 1024
                                + (size_t)brr * 1024;
  int bw[4];
#pragma unroll
  for (int sl = 0; sl < 4; sl++) bw[sl] = (2 + bp) * 8192 + br * 64 + ((sl ^ (br & 3)) << 4);
  const float* pRow = probs + ((size_t)b * NN + (n0 + ar)) * NN;
  const size_t ctRow = (size_t)(n0 + ar) * NN;
  // ---- frag read offsets (same swizzle as write side) ----
  const int off16 = ((lane >> 4) ^ (lane & 3)) << 4;
  int rA[4], rB[4];
#pragma unroll
  for (int m = 0; m < 4; m++) rA[m] = (wm * 64 + m * 16 + (lane & 15)) * 64 + off16;
#pragma unroll
  for (int j = 0; j < 4; j++) rB[j] = (wn * 64 + j * 16 + (lane & 15)) * 64 + off16 + 16384;
  f32x4 acc[4][4] = {};
  float4 pv[4], cv[4], bv[4];
  auto loadK = [&](int kc) {
    const int pl = kc >> 4;                    // 0 -> k=1 half, 1 -> k=2 half
    const int mb = (kc & 15) * 32 + ahf * 16;  // m within half
    const float* pp = pRow + mb;
    const float* cp = ct + (size_t)(pl + 1) * (NN * NN) + ctRow + mb;
#pragma unroll
    for (int q = 0; q < 4; q++) {
      pv[q] = *(const float4*)(pp + q * 4);
      cv[q] = *(const float4*)(cp + q * 4);
    }
    const unsigned short* bb = gB + kc * 32;
#pragma unroll
    for (int q = 0; q < 4; q++) bv[q] = *(const float4*)(bb + q * 8);
  };
  auto stage = [&](char* base) {
#pragma unroll
    for (int sl = 0; sl < 4; sl++) *(float4*)(base + bw[sl]) = bv[sl];
    float a[16];
#pragma unroll
    for (int q = 0; q < 4; q++) {
      a[q * 4 + 0] = pv[q].x * cv[q].x;
      a[q * 4 + 1] = pv[q].y * cv[q].y;
      a[q * 4 + 2] = pv[q].z * cv[q].z;
      a[q * 4 + 3] = pv[q].w * cv[q].w;
    }
    unsigned int hw[8], lw[8];
#pragma unroll
    for (int q = 0; q < 8; q++) {
      unsigned short h0 = bf16rne(a[q * 2]), h1 = bf16rne(a[q * 2 + 1]);
      hw[q] = (unsigned int)h0 | ((unsigned int)h1 << 16);
      unsigned short l0 = bf16rne(a[q * 2] - bfval(h0));
      unsigned short l1 = bf16rne(a[q * 2 + 1] - bfval(h1));
      lw[q] = (unsigned int)l0 | ((unsigned int)l1 << 16);
    }
    *(uint4*)(base + aw0) = make_uint4(hw[0], hw[1], hw[2], hw[3]);
    *(uint4*)(base + aw1) = make_uint4(hw[4], hw[5], hw[6], hw[7]);
    *(uint4*)(base + 8192 + aw0) = make_uint4(lw[0], lw[1], lw[2], lw[3]);
    *(uint4*)(base + 8192 + aw1) = make_uint4(lw[4], lw[5], lw[6], lw[7]);
  };
  loadK(0);
  stage(lds);
  __syncthreads();
  for (int kc = 0; kc < 32; kc++) {
    char* cur = lds + ((kc & 1) << 15);
    if (kc < 31) loadK(kc + 1);
    bf16x8 ah[4], al[4], bh[4], blr[4];
#pragma unroll
    for (int m = 0; m < 4; m++) {
      ah[m] = *(const bf16x8*)(cur + rA[m]);
      al[m] = *(const bf16x8*)(cur + rA[m] + 8192);
    }
#pragma unroll
    for (int j = 0; j < 4; j++) {
      bh[j] = *(const bf16x8*)(cur + rB[j]);
      blr[j] = *(const bf16x8*)(cur + rB[j] + 8192);
    }
#pragma unroll
    for (int m = 0; m < 4; m++)
#pragma unroll
      for (int j = 0; j < 4; j++) {
        acc[m][j] = __builtin_amdgcn_mfma_f32_16x16x32_bf16(ah[m], bh[j], acc[m][j], 0, 0, 0);
        acc[m][j] = __builtin_amdgcn_mfma_f32_16x16x32_bf16(al[m], bh[j], acc[m][j], 0, 0, 0);
        acc[m][j] = __builtin_amdgcn_mfma_f32_16x16x32_bf16(ah[m], blr[j], acc[m][j], 0, 0, 0);
      }
    if (kc < 31) stage(lds + (((kc & 1) ^ 1) << 15));
    __syncthreads();
  }
#pragma unroll
  for (int m = 0; m < 4; m++) {
    const int nb = n0 + wm * 64 + m * 16 + (lane >> 4) * 4;
#pragma unroll
    for (int j = 0; j < 4; j++) {
      const int c = c0 + wn * 64 + j * 16 + (lane & 15);
      if (c < NFT) {
        const float* Yc = Y0 + ((size_t)bl * NFT + c) * NN;
#pragma unroll
        for (int rg = 0; rg < 4; rg++) {
          const int n = nb + rg;
          if (n < NN) {
            float v = acc[m][j][rg] + sd[(size_t)b * NN + n] * Yc[n];
            outX[((size_t)b * NN + n) * NFT + c] = fmaxf(v, 0.f);
          }
        }
      }
    }
  }
}

// ---- layer norm over (C,N,T) per sample; one block per b ----
__global__ __launch_bounds__(256) void k_ln_stat(const float* x, float* stat, int M) {
  int b = blockIdx.x;
  const float* xp = x + (size_t)b * M;
  float s1 = 0.f, s2 = 0.f;
  for (int i = threadIdx.x; i < M; i += 256) {
    float v = xp[i]; s1 += v; s2 += v * v;
  }
  __shared__ float r1[256], r2[256];
  int tid = threadIdx.x;
  r1[tid] = s1; r2[tid] = s2;
  __syncthreads();
  for (int s = 128; s > 0; s >>= 1) {
    if (tid < s) { r1[tid] += r1[tid + s]; r2[tid] += r2[tid + s]; }
    __syncthreads();
  }
  if (tid == 0) {
    float mean = r1[0] / M;
    float var = r2[0] / M - mean * mean;
    stat[b * 2] = mean;
    stat[b * 2 + 1] = rsqrtf(var + 1e-5f);
  }
}
__global__ void k_ln_norm(const float* x, const float* stat, const float* wn, const float* bn,
                          float* out, int M) {
  int total = NB * M;
  int idx = blockIdx.x * 256 + threadIdx.x;
  if (idx >= total) return;
  int b = idx / M;
  int i = idx % M;
  float y = (x[idx] - stat[b * 2]) * stat[b * 2 + 1];
  out[idx] = y * wn[i] + bn[i];
}

// ---- final head ----
__global__ void k_fin1(const float* h, const float* w, const float* bias, const float* skip,
                       float* out) {
  int total = NB * 64 * NN;
  int idx = blockIdx.x * 256 + threadIdx.x;
  if (idx >= total) return;
  int n = idx % NN;
  int c = (idx / NN) % 64;
  int b = idx / (NN * 64);
  float v = bias[c];
  for (int ci = 0; ci < 32; ci++) v += w[c * 32 + ci] * h[(b * NF + ci) * NN + n];
  v += skip[((size_t)(b * 64 + c) * NN + n) * 7 + 6];
  out[idx] = fmaxf(v, 0.f);
}
__global__ void k_fin2(const float* in, const float* w, const float* bias, float* out) {
  int total = NB * 128 * NN;
  int idx = blockIdx.x * 256 + threadIdx.x;
  if (idx >= total) return;
  int n = idx % NN;
  int c = (idx / NN) % 128;
  int b = idx / (NN * 128);
  float v = bias[c];
  for (int ci = 0; ci < 64; ci++) v += w[c * 64 + ci] * in[(b * 64 + ci) * NN + n];
  out[idx] = fmaxf(v, 0.f);
}
__global__ void k_fin3(const float* in, const float* w, const float* bias, float* out) {
  int total = NB * 12 * NN;
  int idx = blockIdx.x * 256 + threadIdx.x;
  if (idx >= total) return;
  int n = idx % NN;
  int c = (idx / NN) % 12;
  int b = idx / (NN * 12);
  float v = bias[c];
  for (int ci = 0; ci < 128; ci++) v += w[c * 128 + ci] * in[(b * 128 + ci) * NN + n];
  out[idx] = v;
}

#define G1(tot) dim3((unsigned)(((tot) + 255) / 256)), dim3(256), 0, stream

extern "C" void kernel_launch(void* const* d_in, const int* in_sizes, int n_in,
                              void* d_out, int out_size, void* d_ws, size_t ws_size,
                              hipStream_t stream) {
  (void)in_sizes; (void)n_in; (void)out_size; (void)ws_size;
  auto I = [&](int i) { return (const float*)d_in[i]; };
  float* W = (float*)d_ws;
  size_t off = 0;
  auto alloc = [&](size_t nel) { float* p = W + off; off += nel; return p; };

  float* bufA  = alloc(9728000);   // h / residual [B,32,N,19max]
  float* bufB  = alloc(9728000);   // h after fc1; later cheb output (t-major, in place)
  float* bufC  = alloc(9728000);   // x_tat -> s1T -> probs (in-place softmax)
  float* bufSK = alloc(7168000);   // skip [B,64,N,7]
  float* skip0 = alloc(1024000);   // skip [B,64,N,1]; dead after layer-0 skipconv
  float* P1    = alloc(9728000);   // s0; dead after k_gemm_vs (within each layer)
  float* CT    = alloc(750000);    // chebT
  float* VST   = alloc(250000);    // vs transposed (per layer)
  float* TL1   = alloc(19456);
  float* TLH   = alloc(304000);
  float* TRH   = alloc(304000);
  float* TE    = alloc(11552);
  float* TE0   = alloc(11552);     // e0 intermediate
  float* SL1   = alloc(512000);
  float* SLH   = alloc(304000);
  float* SRH   = alloc(304000);
  float* ACC   = alloc(64);
  float* SD    = alloc(16000);     // sd[b][n] = p[b,n,n]
  float* THT   = alloc(3072);      // thetaT[k][f2][f]

  // cheb staging: reuse skip0+P1 (contiguous 10,752,000 floats, dead at cheb time).
  constexpr int GB = 11;
  float* STG = skip0;
  unsigned short* Bb = (unsigned short*)STG;   // [bl][2][NFT][1024] bf16
  float* Y0f = STG + 6848512;                  // [bl][NFT][500] fp32

  float* P2 = bufC;                // s1T/probs live in bufC through the cheb GEMM
  float* F1 = P1;                  // [B,64,N] final head, after staging is dead
  float* F2 = P1 + 1024000;        // [B,128,N]

  k_start<<<G1(NB * NF * NN * 19)>>>(I(0), I(1), I(2), bufA);
  k_skip0<<<G1(NB * 64 * NN)>>>(I(0), I(3), I(4), skip0);
  k_chebT<<<G1(3 * NN * NN)>>>(I(59), CT);
  k_thetaT<<<G1(3 * NF * NF)>>>(I(60), THT);

  dim3 ggt((NN + 7) / 8, NB), bgt(256);
  auto gtufc = [&](int Ti, int To, const float* hin, const float* fw, const float* fb,
                   const float* res, float* o) {
    if (Ti == 19 && To == 19)
      k_gtufc_t<19, 19><<<ggt, bgt, 0, stream>>>(hin, I(5), I(6), I(7), I(8), I(9), I(10), fw, fb, res, o);
    else if (Ti == 13 && To == 13)
      k_gtufc_t<13, 13><<<ggt, bgt, 0, stream>>>(hin, I(5), I(6), I(7), I(8), I(9), I(10), fw, fb, res, o);
    else
      k_gtufc_t<7, 7><<<ggt, bgt, 0, stream>>>(hin, I(5), I(6), I(7), I(8), I(9), I(10), fw, fb, res, o);
  };
  auto gtufcx = [&](int Ti, int To, const float* hin, const float* fw, const float* fb,
                    const float* res, float* o) {
    if (Ti == 19)
      k_gtufc_x<19, 13><<<ggt, bgt, 0, stream>>>(hin, I(5), I(6), I(7), I(8), I(9), I(10), fw, fb, res, o);
    else if (Ti == 13)
      k_gtufc_x<13, 7><<<ggt, bgt, 0, stream>>>(hin, I(5), I(6), I(7), I(8), I(9), I(10), fw, fb, res, o);
    else
      k_gtufc_x<7, 1><<<ggt, bgt, 0, stream>>>(hin, I(5), I(6), I(7), I(8), I(9), I(10), fw, fb, res, o);
  };

  const int Tin[3] = {19, 13, 7}, Tout[3] = {13, 7, 1};
  for (int i = 0; i < 3; i++) {
    int Ti = Tin[i], To = Tout[i];
    // gated TCN + fc1 + relu-add : bufA -> bufB
    gtufc(Ti, Ti, bufA, I(11 + 2 * i), I(12 + 2 * i), nullptr, bufB);
    // skip conv
    if (i == 0)
      k_skipconv_t<19, 13><<<ggt, bgt, 0, stream>>>(bufB, I(23), I(24), skip0, 1, bufSK);
    else if (i == 1)
      k_skipconv_t<13, 7><<<ggt, bgt, 0, stream>>>(bufB, I(25), I(26), bufSK, 7, bufSK);
    else
      k_skipconv_t<7, 1><<<ggt, bgt, 0, stream>>>(bufB, I(27), I(28), bufSK, 7, bufSK);
    // temporal attention
    int ba = 29 + i * 10;
    k_zero<<<G1(NB * Ti * NF)>>>(TL1, NB * Ti * NF);
    k_ta_lhs1b<<<dim3(20, NB), dim3(256), 0, stream>>>(bufB, I(ba + 0), TL1, Ti);
    k_ta_lhs<<<G1(NB * Ti * NN)>>>(TL1, I(ba + 1), TLH, Ti);
    k_ta_rhs<<<G1(NB * NN * Ti)>>>(bufB, I(ba + 2), TRH, Ti);
    k_ta_e0<<<dim3(Ti, NB), dim3(256), 0, stream>>>(TLH, TRH, I(ba + 3), TE0, Ti);
    k_ta_att2<<<dim3(NB), dim3(256), 0, stream>>>(TE0, I(ba + 4), TE, Ti);
    k_xtat<<<G1(NB * NF * NN * Ti)>>>(TE, bufB, bufC, Ti);  // x_tat into bufC
    // spatial attention
    k_sa_lhs1<<<G1(NB * NN * NF)>>>(bufC, I(ba + 5), SL1, Ti);
    k_sa_lhs<<<G1(NB * NN * Ti)>>>(SL1, I(ba + 6), SLH, Ti);
    k_sa_rhs<<<G1(NB * Ti * NN)>>>(bufC, I(ba + 7), SRH, Ti);
    k_sa_prod<<<G1(NB * NN * NN)>>>(SLH, SRH, I(ba + 8), P1, Ti);  // x_tat consumed
    k_transpose<<<dim3(16, 16), dim3(256), 0, stream>>>(I(ba + 9), VST);
    {
      dim3 gg((NN + 127) / 128, 8, NB);
      k_gemm_vs<<<gg, dim3(256), 0, stream>>>(VST, P1, P2);  // s1T into bufC; P1 free
    }
    // ==== cheb conv via bf16x3 MFMA: in-place softmax + on-the-fly A + b-groups ====
    int NFT = NF * Ti;
    k_smax_ip<<<dim3(NN, NB), dim3(256), 0, stream>>>(P2, SD);  // probs in place in bufC
    for (int b0 = 0; b0 < NB; b0 += GB) {
      int gsz = (NB - b0 < GB) ? (NB - b0) : GB;
      k_prepY2<<<dim3(Ti, gsz), dim3(256), 0, stream>>>(bufB, THT, Ti, b0, Bb, Y0f);
      dim3 gm((NFT + 127) / 128, 4, gsz);
      k_cheb_mfma2<<<gm, dim3(256), 0, stream>>>(Bb, P2, CT, Y0f, SD, b0, NFT, bufB);
    }
    // second gated TCN (t-major input) + fc2 + relu-add + residual : bufB (+bufA) -> bufC
    gtufcx(Ti, To, bufB, I(17 + 2 * i), I(18 + 2 * i), bufA, bufC);
    // layer norm: bufC -> bufA
    int M = NF * NN * To;
    k_ln_stat<<<dim3(NB), dim3(256), 0, stream>>>(bufC, ACC, M);
    k_ln_norm<<<G1(NB * M)>>>(bufC, ACC, I(61 + 2 * i), I(62 + 2 * i), bufA, M);
  }
  // final head
  k_fin1<<<G1(NB * 64 * NN)>>>(bufA, I(67), I(68), bufSK, F1);
  k_fin2<<<G1(NB * 128 * NN)>>>(F1, I(69), I(70), F2);
  k_fin3<<<G1(NB * 12 * NN)>>>(F2, I(71), I(72), (float*)d_out);
}

// Round 5
// 5693.795 us; speedup vs baseline: 1.1032x; 1.1032x over previous
//
#include <hip/hip_runtime.h>
#include <hip/hip_bf16.h>
#include <math.h>

#define NB 32      // batch
#define NN 500     // nodes
#define NF 32      // channels

typedef float f32x4 __attribute__((ext_vector_type(4)));
typedef short bf16x8 __attribute__((ext_vector_type(8)));

__device__ __forceinline__ float sigf(float x) { return 1.0f / (1.0f + __expf(-x)); }
// fast tanh: |err| ~1e-7, no overflow (e in (0,1])
__device__ __forceinline__ float tanhf_fast(float x) {
  float e = __expf(-2.0f * fabsf(x));
  float r = (1.0f - e) / (1.0f + e);
  return copysignf(r, x);
}

__device__ __forceinline__ unsigned short bf16rne(float x) {
  unsigned int u = __float_as_uint(x);
  unsigned int r = u + 0x7FFFu + ((u >> 16) & 1u);
  return (unsigned short)(r >> 16);
}
__device__ __forceinline__ float bfval(unsigned short h) {
  return __uint_as_float((unsigned int)h << 16);
}

__global__ void k_zero(float* p, int n) {
  int i = blockIdx.x * 256 + threadIdx.x;
  if (i < n) p[i] = 0.f;
}

// h[b,c,n,t] = b_start[c] + sum_ci w_start[c,ci]*padded_x[b,ci,n,t]; pad 7 zeros at front (19)
__global__ void k_start(const float* x, const float* w, const float* bias, float* h) {
  int idx = blockIdx.x * 256 + threadIdx.x;
  const int total = NB * NF * NN * 19;
  if (idx >= total) return;
  int t = idx % 19;
  int n = (idx / 19) % NN;
  int c = (idx / (19 * NN)) % NF;
  int b = idx / (19 * NN * NF);
  float v = bias[c];
  if (t >= 7) {
    int tx = t - 7;
    v += w[c * 2 + 0] * x[((size_t)(b * 2 + 0) * NN + n) * 12 + tx];
    v += w[c * 2 + 1] * x[((size_t)(b * 2 + 1) * NN + n) * 12 + tx];
  }
  h[idx] = v;
}

// skip0[b,c,n] = b_sk0[c] + sum_{ci,k>=7} w_sk0[c,ci,k]*x[b,ci,n,k-7]
__global__ void k_skip0(const float* x, const float* w, const float* bias, float* s0) {
  int idx = blockIdx.x * 256 + threadIdx.x;
  const int total = NB * 64 * NN;
  if (idx >= total) return;
  int n = idx % NN;
  int c = (idx / NN) % 64;
  int b = idx / (NN * 64);
  float v = bias[c];
  for (int ci = 0; ci < 2; ci++)
    for (int k = 7; k < 19; k++)
      v += w[(c * 2 + ci) * 19 + k] * x[((size_t)(b * 2 + ci) * NN + n) * 12 + (k - 7)];
  s0[idx] = v;
}

// ---- fused gated-TCN + fc; gtu_seg generalized over LDS strides (TS=time, CS=channel) ----
// j-outer / t-inner: L independent accumulator chains per gate (breaks the 4-cyc FMA
// dependency stall seen as VALUBusy~49%). Per-accumulator op order identical to t-outer.
template<int K, int L, int TS, int CS, int TCAT, int TO>
__device__ __forceinline__ void gtu_seg(const float* __restrict__ wseg,
                                        const float* __restrict__ bg,
                                        const float* __restrict__ hbase,
                                        const float* __restrict__ fw,
                                        float (&oacc)[TO], int c, int tbase) {
  float y0[L], y1[L];
#pragma unroll
  for (int t = 0; t < L; t++) { y0[t] = 0.f; y1[t] = 0.f; }
#pragma unroll 2
  for (int ci = 0; ci < NF; ci++) {
    float hrow[L + K - 1];
#pragma unroll
    for (int t = 0; t < L + K - 1; t++) hrow[t] = hbase[ci * CS + t * TS];
    float w0[K], w1[K];
#pragma unroll
    for (int j = 0; j < K; j++) {
      w0[j] = wseg[(c * NF + ci) * K + j];
      w1[j] = wseg[((c + 32) * NF + ci) * K + j];
    }
#pragma unroll
    for (int j = 0; j < K; j++)
#pragma unroll
      for (int t = 0; t < L; t++) {
        y0[t] += w0[j] * hrow[t + j];
        y1[t] += w1[j] * hrow[t + j];
      }
  }
  float b0 = bg[c], b1 = bg[c + 32];
#pragma unroll
  for (int t = 0; t < L; t++) {
    float tcv = tanhf_fast(y0[t] + b0) * sigf(y1[t] + b1);
#pragma unroll
    for (int o = 0; o < TO; o++) oacc[o] += tcv * fw[o * TCAT + tbase + t];
  }
}

// standard-layout input h[b,c,n,t]
template<int TI, int TO>
__global__ __launch_bounds__(256) void k_gtufc_t(
    const float* __restrict__ h,
    const float* __restrict__ wg3, const float* __restrict__ bg3,
    const float* __restrict__ wg5, const float* __restrict__ bg5,
    const float* __restrict__ wg7, const float* __restrict__ bg7,
    const float* __restrict__ fw, const float* __restrict__ fb,
    const float* __restrict__ res, float* __restrict__ out) {
  constexpr int TCAT = 3 * TI - 12;
  constexpr int TP = (TI + 3) & ~3;
  constexpr int OFF = TI - TO;
  const int b = blockIdx.y;
  const int n0 = blockIdx.x * 8;
  const int tid = threadIdx.x;
  const int c = tid & 31, nn = tid >> 5;
  const int n = n0 + nn;
  __shared__ float hs[8 * NF * TP];
  for (int l = tid; l < 8 * NF * TP; l += 256) {
    int t = l % TP;
    int ci = (l / TP) % NF;
    int n2 = l / (TP * NF);
    int gn = n0 + n2;
    hs[l] = (t < TI && gn < NN) ? h[((size_t)(b * NF + ci) * NN + gn) * TI + t] : 0.f;
  }
  __syncthreads();
  const float* hbase = hs + nn * NF * TP;
  float oacc[TO];
#pragma unroll
  for (int o = 0; o < TO; o++) oacc[o] = 0.f;
  gtu_seg<3, TI - 2, 1, TP, TCAT, TO>(wg3, bg3, hbase, fw, oacc, c, 0);
  gtu_seg<5, TI - 4, 1, TP, TCAT, TO>(wg5, bg5, hbase, fw, oacc, c, TI - 2);
  gtu_seg<7, TI - 6, 1, TP, TCAT, TO>(wg7, bg7, hbase, fw, oacc, c, 2 * TI - 6);
  if (n < NN) {
    size_t base = (size_t)(b * NF + c) * NN + n;
#pragma unroll
    for (int o = 0; o < TO; o++) {
      float v = fmaxf(hbase[c * TP + OFF + o] + oacc[o] + fb[o], 0.f);
      if (res) v += res[base * TI + OFF + o];
      out[base * TO + o] = v;
    }
  }
}

// t-major input hX[b][n][t*NF+f] (cheb output layout); output standard layout
template<int TI, int TO>
__global__ __launch_bounds__(256) void k_gtufc_x(
    const float* __restrict__ hX,
    const float* __restrict__ wg3, const float* __restrict__ bg3,
    const float* __restrict__ wg5, const float* __restrict__ bg5,
    const float* __restrict__ wg7, const float* __restrict__ bg7,
    const float* __restrict__ fw, const float* __restrict__ fb,
    const float* __restrict__ res, float* __restrict__ out) {
  constexpr int TCAT = 3 * TI - 12;
  constexpr int NFT = NF * TI;
  constexpr int OFF = TI - TO;
  const int b = blockIdx.y;
  const int n0 = blockIdx.x * 8;
  const int tid = threadIdx.x;
  const int c = tid & 31, nn = tid >> 5;
  const int n = n0 + nn;
  __shared__ float hs[8 * NFT];
  for (int l = tid; l < 8 * NFT; l += 256) {
    int n2 = l / NFT, l2 = l % NFT;
    int gn = n0 + n2;
    hs[l] = (gn < NN) ? hX[(size_t)(b * NN + gn) * NFT + l2] : 0.f;
  }
  __syncthreads();
  const float* hbase = hs + nn * NFT;
  float oacc[TO];
#pragma unroll
  for (int o = 0; o < TO; o++) oacc[o] = 0.f;
  gtu_seg<3, TI - 2, NF, 1, TCAT, TO>(wg3, bg3, hbase, fw, oacc, c, 0);
  gtu_seg<5, TI - 4, NF, 1, TCAT, TO>(wg5, bg5, hbase, fw, oacc, c, TI - 2);
  gtu_seg<7, TI - 6, NF, 1, TCAT, TO>(wg7, bg7, hbase, fw, oacc, c, 2 * TI - 6);
  if (n < NN) {
    size_t base = (size_t)(b * NF + c) * NN + n;
#pragma unroll
    for (int o = 0; o < TO; o++) {
      float v = fmaxf(hbase[(OFF + o) * NF + c] + oacc[o] + fb[o], 0.f);
      if (res) v += res[base * TI + OFF + o];
      out[base * TO + o] = v;
    }
  }
}

// ---- skip conv, LDS h staging, weights in registers, K unrolled ----
template<int TI, int K>
__global__ __launch_bounds__(256) void k_skipconv_t(
    const float* __restrict__ h, const float* __restrict__ w,
    const float* __restrict__ bias, const float* __restrict__ prev, int prevT,
    float* __restrict__ out) {
  constexpr int TP = (TI + 3) & ~3;
  const int b = blockIdx.y, n0 = blockIdx.x * 8, tid = threadIdx.x;
  __shared__ float hs[8 * NF * TP];
  for (int l = tid; l < 8 * NF * TP; l += 256) {
    int t = l % TP;
    int ci = (l / TP) % NF;
    int n2 = l / (TP * NF);
    int gn = n0 + n2;
    hs[l] = (t < TI && gn < NN) ? h[((size_t)(b * NF + ci) * NN + gn) * TI + t] : 0.f;
  }
  __syncthreads();
  const int c = tid & 63, ng = tid >> 6;
  float bv = bias[c];
  float o[2][7];
#pragma unroll
  for (int q = 0; q < 2; q++)
#pragma unroll
    for (int t = 0; t < 7; t++) o[q][t] = bv;
  for (int ci = 0; ci < NF; ci++) {
    float wv[K];
#pragma unroll
    for (int j = 0; j < K; j++) wv[j] = w[(c * NF + ci) * K + j];
#pragma unroll
    for (int q = 0; q < 2; q++) {
      const float* hp = hs + ((ng + q * 4) * NF + ci) * TP;
      float hl[6 + K];
#pragma unroll
      for (int t = 0; t < 6 + K; t++) hl[t] = hp[t];
#pragma unroll
      for (int j = 0; j < K; j++)
#pragma unroll
        for (int t = 0; t < 7; t++) o[q][t] += wv[j] * hl[t + j];
    }
  }
#pragma unroll
  for (int q = 0; q < 2; q++) {
    int n = n0 + ng + q * 4;
    if (n < NN) {
      size_t base = (size_t)(b * 64 + c) * NN + n;
#pragma unroll
      for (int t = 0; t < 7; t++) {
        float pv = (prevT == 1) ? prev[base] : prev[base * 7 + t];
        out[base * 7 + t] = o[q][t] + pv;
      }
    }
  }
}

// ---- temporal attention ----
// lhs1[b][t][f] += sum_{n in chunk} u1[n]*h[b,f,n,t]; chunked LDS staging + atomics.
__global__ __launch_bounds__(256) void k_ta_lhs1b(const float* __restrict__ h,
                                                  const float* __restrict__ u1,
                                                  float* __restrict__ out, int T) {
  const int ch = blockIdx.x, b = blockIdx.y;
  const int n0 = ch * 25;
  const int tid = threadIdx.x;
  __shared__ float hs[25 * NF * 19];  // [n][f][t]
  const int tot = 25 * NF * T;
  for (int l = tid; l < tot; l += 256) {
    int t = l % T;
    int f = (l / T) % NF;
    int n2 = l / (T * NF);
    hs[(n2 * NF + f) * T + t] = h[((size_t)(b * NF + f) * NN + n0 + n2) * T + t];
  }
  __syncthreads();
  for (int l2 = tid; l2 < NF * T; l2 += 256) {
    int f = l2 / T, t = l2 % T;
    float acc = 0.f;
#pragma unroll 5
    for (int n2 = 0; n2 < 25; n2++)
      acc += hs[(n2 * NF + f) * T + t] * u1[n0 + n2];
    atomicAdd(&out[(b * T + t) * NF + f], acc);
  }
}
__global__ void k_ta_lhs(const float* l1, const float* u2, float* out, int T) {
  int total = NB * T * NN;
  int idx = blockIdx.x * 256 + threadIdx.x;
  if (idx >= total) return;
  int n = idx % NN;
  int t = (idx / NN) % T;
  int b = idx / (NN * T);
  float acc = 0.f;
  for (int f = 0; f < NF; f++) acc += l1[(b * T + t) * NF + f] * u2[f * NN + n];
  out[idx] = acc;  // (b,t,n)
}
__global__ void k_ta_rhs(const float* h, const float* u3, float* out, int T) {
  int total = NB * NN * T;
  int idx = blockIdx.x * 256 + threadIdx.x;
  if (idx >= total) return;
  int t = idx % T;
  int n = (idx / T) % NN;
  int b = idx / (T * NN);
  float acc = 0.f;
  for (int f = 0; f < NF; f++) acc += u3[f] * h[((size_t)(b * NF + f) * NN + n) * T + t];
  out[idx] = acc;  // (b,n,t)
}
// e0[b][t][m] = sigf(sum_n lhs[b,t,n]*rhs[b,n,m] + be[t,m]); block per (t,b)
__global__ __launch_bounds__(256) void k_ta_e0(const float* __restrict__ lhs,
                                               const float* __restrict__ rhs,
                                               const float* __restrict__ be,
                                               float* __restrict__ e0g, int T) {
  const int t = blockIdx.x, b = blockIdx.y, tid = threadIdx.x;
  const float* lp = lhs + ((size_t)b * T + t) * NN;
  const float* rp = rhs + (size_t)b * NN * T;
  float acc[19];
#pragma unroll
  for (int m = 0; m < 19; m++) acc[m] = 0.f;
  for (int n = tid; n < NN; n += 256) {
    float lv = lp[n];
    const float* rr = rp + (size_t)n * T;
    for (int m = 0; m < T; m++) acc[m] += lv * rr[m];
  }
  __shared__ float red[256 * 20];
  for (int m = 0; m < T; m++) red[tid * 20 + m] = acc[m];
  __syncthreads();
  for (int s = 128; s > 0; s >>= 1) {
    if (tid < s)
      for (int m = 0; m < T; m++) red[tid * 20 + m] += red[(tid + s) * 20 + m];
    __syncthreads();
  }
  if (tid < T)
    e0g[((size_t)b * T + t) * T + tid] = sigf(red[tid] + be[t * T + tid]);
}
// e1 = ve@e0; e = softmax over t. one block per b.
__global__ __launch_bounds__(256) void k_ta_att2(const float* __restrict__ e0g,
                                                 const float* __restrict__ ve,
                                                 float* __restrict__ e, int T) {
  int b = blockIdx.x, tid = threadIdx.x;
  __shared__ float e0[19 * 19];
  __shared__ float e1[19 * 19];
  int TT = T * T;
  for (int l = tid; l < TT; l += 256) e0[l] = e0g[(size_t)b * TT + l];
  __syncthreads();
  for (int l = tid; l < TT; l += 256) {
    int t = l / T, m = l % T;
    float acc = 0.f;
    for (int j = 0; j < T; j++) acc += ve[t * T + j] * e0[j * T + m];
    e1[l] = acc;
  }
  __syncthreads();
  if (tid < T) {
    int m = tid;
    float mx = -1e30f;
    for (int t = 0; t < T; t++) mx = fmaxf(mx, e1[t * T + m]);
    float s = 0.f;
    for (int t = 0; t < T; t++) s += __expf(e1[t * T + m] - mx);
    float inv = 1.f / s;
    for (int t = 0; t < T; t++)
      e[((size_t)b * T + t) * T + m] = __expf(e1[t * T + m] - mx) * inv;
  }
}
// xt[b,f,n,t] = sum_j e[b,t,j] * h[b,f,n,j]
__global__ void k_xtat(const float* e, const float* h, float* xt, int T) {
  int total = NB * NF * NN * T;
  int idx = blockIdx.x * 256 + threadIdx.x;
  if (idx >= total) return;
  int t = idx % T;
  int n = (idx / T) % NN;
  int f = (idx / (T * NN)) % NF;
  int b = idx / (T * NN * NF);
  const float* hp = h + ((size_t)(b * NF + f) * NN + n) * T;
  float acc = 0.f;
  for (int j = 0; j < T; j++) acc += e[(b * T + t) * T + j] * hp[j];
  xt[idx] = acc;
}

// ---- spatial attention ----
__global__ void k_sa_lhs1(const float* xt, const float* w1, float* out, int T) {
  int total = NB * NN * NF;
  int idx = blockIdx.x * 256 + threadIdx.x;
  if (idx >= total) return;
  int f = idx % NF;
  int n = (idx / NF) % NN;
  int b = idx / (NF * NN);
  const float* xp = xt + ((size_t)(b * NF + f) * NN + n) * T;
  float acc = 0.f;
  for (int t = 0; t < T; t++) acc += xp[t] * w1[t];
  out[(b * NN + n) * NF + f] = acc;
}
__global__ void k_sa_lhs(const float* l1, const float* w2, float* out, int T) {
  int total = NB * NN * T;
  int idx = blockIdx.x * 256 + threadIdx.x;
  if (idx >= total) return;
  int t = idx % T;
  int n = (idx / T) % NN;
  int b = idx / (T * NN);
  float acc = 0.f;
  for (int f = 0; f < NF; f++) acc += l1[(b * NN + n) * NF + f] * w2[f * T + t];
  out[idx] = acc;  // (b,n,t)
}
__global__ void k_sa_rhs(const float* xt, const float* w3, float* out, int T) {
  int total = NB * T * NN;
  int idx = blockIdx.x * 256 + threadIdx.x;
  if (idx >= total) return;
  int n = idx % NN;
  int t = (idx / NN) % T;
  int b = idx / (NN * T);
  float acc = 0.f;
  for (int f = 0; f < NF; f++) acc += w3[f] * xt[((size_t)(b * NF + f) * NN + n) * T + t];
  out[idx] = acc;  // (b,t,n)
}
__global__ void k_sa_prod(const float* lhs, const float* rhs, const float* bs, float* s0, int T) {
  int total = NB * NN * NN;
  int idx = blockIdx.x * 256 + threadIdx.x;
  if (idx >= total) return;
  int m = idx % NN;
  int n = (idx / NN) % NN;
  int b = idx / (NN * NN);
  float acc = 0.f;
  for (int t = 0; t < T; t++)
    acc += lhs[((size_t)b * NN + n) * T + t] * rhs[((size_t)b * T + t) * NN + m];
  s0[idx] = sigf(acc + bs[(size_t)n * NN + m]);
}

// 500x500 transpose (for vs)
__global__ __launch_bounds__(256) void k_transpose(const float* in, float* outT) {
  __shared__ float tile[32][33];
  int x0 = blockIdx.x * 32, y0 = blockIdx.y * 32;
  int tx = threadIdx.x & 31, ty8 = threadIdx.x >> 5;
  for (int yy = ty8; yy < 32; yy += 8) {
    int x = x0 + tx, y = y0 + yy;
    tile[yy][tx] = (x < NN && y < NN) ? in[(size_t)y * NN + x] : 0.f;
  }
  __syncthreads();
  for (int yy = ty8; yy < 32; yy += 8) {
    int x = y0 + tx, y = x0 + yy;
    if (x < NN && y < NN) outT[(size_t)y * NN + x] = tile[tx][yy];
  }
}

// s1T[b,c,r] = (vs @ s0[b])[r,c] — 64x128 tile, double-buffered, float4 everywhere
__global__ __launch_bounds__(256) void k_gemm_vs(const float* __restrict__ vsT,
                                                 const float* __restrict__ s0,
                                                 float* __restrict__ s1t) {
  const int b = blockIdx.z;
  const int row0 = blockIdx.y * 64, col0 = blockIdx.x * 128;
  const int tid = threadIdx.x;
  const int tx = tid & 15, ty = tid >> 4;
  __shared__ float smem[6400];      // 2 x (As 16x68 + Bs 16x132)
  float acc[4][8] = {};
  const float* S0 = s0 + (size_t)b * NN * NN;
  const int nch = (NN + 15) / 16;
  float4 pa, pb0, pb1;
  auto loadregs = [&](int k0) {
    {
      int rq = tid & 15, kk = tid >> 4;
      int gk = k0 + kk, gi = row0 + rq * 4;
      float4 v = {0.f, 0.f, 0.f, 0.f};
      if (gk < NN && gi < NN) v = *(const float4*)&vsT[(size_t)gk * NN + gi];
      pa = v;
    }
#pragma unroll
    for (int it = 0; it < 2; it++) {
      int l = tid + it * 256;
      int q = l & 31, kk = l >> 5;
      int gk = k0 + kk, gc = col0 + q * 4;
      float4 v = {0.f, 0.f, 0.f, 0.f};
      if (gk < NN && gc < NN) v = *(const float4*)&S0[(size_t)gk * NN + gc];
      if (it == 0) pb0 = v; else pb1 = v;
    }
  };
  auto writebuf = [&](int buf) {
    float* As = smem + buf * 3200;
    float* Bs = As + 1088;
    {
      int rq = tid & 15, kk = tid >> 4;
      *(float4*)&As[kk * 68 + rq * 4] = pa;
    }
#pragma unroll
    for (int it = 0; it < 2; it++) {
      int l = tid + it * 256;
      int q = l & 31, kk = l >> 5;
      *(float4*)&Bs[kk * 132 + q * 4] = (it == 0) ? pb0 : pb1;
    }
  };
  loadregs(0);
  writebuf(0);
  for (int ch = 0; ch < nch; ch++) {
    int cur = ch & 1;
    if (ch + 1 < nch) loadregs((ch + 1) * 16);
    __syncthreads();
    const float* As = smem + cur * 3200;
    const float* Bs = As + 1088;
#pragma unroll
    for (int kk = 0; kk < 16; kk++) {
      float4 a4 = *(const float4*)&As[kk * 68 + ty * 4];
      float4 b0 = *(const float4*)&Bs[kk * 132 + tx * 4];
      float4 b1 = *(const float4*)&Bs[kk * 132 + 64 + tx * 4];
      float a[4] = {a4.x, a4.y, a4.z, a4.w};
      float bb[8] = {b0.x, b0.y, b0.z, b0.w, b1.x, b1.y, b1.z, b1.w};
#pragma unroll
      for (int i = 0; i < 4; i++)
#pragma unroll
        for (int j = 0; j < 8; j++) acc[i][j] += a[i] * bb[j];
    }
    if (ch + 1 < nch) writebuf((ch + 1) & 1);
  }
  float* S1 = s1t + (size_t)b * NN * NN;
  int gi0 = row0 + ty * 4;
  if (gi0 < NN) {  // NN%4==0 so gi0<NN implies gi0+3<NN
#pragma unroll
    for (int j = 0; j < 8; j++) {
      int gc = col0 + (j < 4 ? tx * 4 + j : 64 + tx * 4 + (j - 4));
      if (gc < NN) {
        float4 v = {acc[0][j], acc[1][j], acc[2][j], acc[3][j]};
        *(float4*)&S1[(size_t)gc * NN + gi0] = v;
      }
    }
  }
}

// chebT[k,n,m] = cheb[k,m,n]
__global__ void k_chebT(const float* cheb, float* ct) {
  int total = 3 * NN * NN;
  int idx = blockIdx.x * 256 + threadIdx.x;
  if (idx >= total) return;
  int m = idx % NN;
  int n = (idx / NN) % NN;
  int k = idx / (NN * NN);
  ct[idx] = cheb[((size_t)k * NN + m) * NN + n];
}

// thetaT[k][f2][f] = theta[k][f][f2] (for vector-load access in k_prepY2)
__global__ void k_thetaT(const float* theta, float* tht) {
  int idx = blockIdx.x * 256 + threadIdx.x;
  if (idx >= 3 * NF * NF) return;
  int f = idx & 31, f2 = (idx >> 5) & 31, k = idx >> 10;
  tht[idx] = theta[(k * NF + f) * NF + f2];
}

// ==== cheb path: in-place softmax, on-the-fly A, full-batch-group launches ====

// softmax in place over each row of s1t (probs stay in bufC); extracts sd[b][n] = p[n,n]
__global__ __launch_bounds__(256) void k_smax_ip(float* __restrict__ s1t,
                                                 float* __restrict__ sd) {
  const int n = blockIdx.x, b = blockIdx.y, tid = threadIdx.x;
  float* S = s1t + ((size_t)b * NN + n) * NN;
  __shared__ float red[256];
  float mx = -1e30f;
  for (int i = tid; i < NN; i += 256) mx = fmaxf(mx, S[i]);
  red[tid] = mx;
  __syncthreads();
  for (int s = 128; s > 0; s >>= 1) {
    if (tid < s) red[tid] = fmaxf(red[tid], red[tid + s]);
    __syncthreads();
  }
  mx = red[0];
  __syncthreads();
  float sum = 0.f;
  for (int i = tid; i < NN; i += 256) sum += __expf(S[i] - mx);
  red[tid] = sum;
  __syncthreads();
  for (int s = 128; s > 0; s >>= 1) {
    if (tid < s) red[tid] += red[tid + s];
    __syncthreads();
  }
  float inv = 1.f / red[0];
  for (int i = tid; i < NN; i += 256) {
    float v = __expf(S[i] - mx) * inv;
    S[i] = v;
    if (i == n) sd[(size_t)b * NN + n] = v;
  }
}

// Y_k = h . theta_k. Y1/Y2 -> bf16 hi/lo B planes [bl][2][NFT][1024]; Y0 -> fp32.
__global__ __launch_bounds__(256) void k_prepY2(const float* __restrict__ h,
                                                const float* __restrict__ tht, int T, int b0,
                                                unsigned short* __restrict__ Bb,
                                                float* __restrict__ Y0) {
  const int t = blockIdx.x, bl = blockIdx.y, b = b0 + bl;
  const int NFT = NF * T;
  const int tid = threadIdx.x;
  __shared__ float hs[NF * NN];  // [f][m]
  for (int l = tid; l < NF * NN; l += 256) {
    int m = l % NN, f = l / NN;
    hs[l] = h[((size_t)(b * NF + f) * NN + m) * T + t];
  }
  __syncthreads();
  const int lane = tid & 63;
  const int w = tid >> 6;
  for (int m = lane; m < 512; m += 64) {
    float hv[NF];
    const bool valid = m < NN;
#pragma unroll
    for (int f = 0; f < NF; f++) hv[f] = valid ? hs[f * NN + m] : 0.f;
    for (int f2q = 0; f2q < 8; f2q++) {
      const int f2 = f2q * 4 + w;
      float a0 = 0.f, a1 = 0.f, a2 = 0.f;
#pragma unroll
      for (int fq = 0; fq < 8; fq++) {
        float4 t0 = *(const float4*)&tht[(0 * NF + f2) * NF + fq * 4];
        float4 t1 = *(const float4*)&tht[(1 * NF + f2) * NF + fq * 4];
        float4 t2 = *(const float4*)&tht[(2 * NF + f2) * NF + fq * 4];
        a0 += hv[fq * 4 + 0] * t0.x + hv[fq * 4 + 1] * t0.y + hv[fq * 4 + 2] * t0.z + hv[fq * 4 + 3] * t0.w;
        a1 += hv[fq * 4 + 0] * t1.x + hv[fq * 4 + 1] * t1.y + hv[fq * 4 + 2] * t1.z + hv[fq * 4 + 3] * t1.w;
        a2 += hv[fq * 4 + 0] * t2.x + hv[fq * 4 + 1] * t2.y + hv[fq * 4 + 2] * t2.z + hv[fq * 4 + 3] * t2.w;
      }
      const int c = t * NF + f2;
      unsigned short* Bhi = Bb + (size_t)bl * NFT * 2048 + (size_t)c * 1024;
      unsigned short* Blo = Bhi + (size_t)NFT * 1024;
      if (valid) Y0[((size_t)bl * NFT + c) * NN + m] = a0;
      unsigned short h1 = bf16rne(a1);
      Bhi[m] = h1;
      Blo[m] = bf16rne(a1 - bfval(h1));
      unsigned short h2 = bf16rne(a2);
      Bhi[512 + m] = h2;
      Blo[512 + m] = bf16rne(a2 - bfval(h2));
    }
  }
}

// C[n,c] = sum_m' A[n,m'] * B[m',c] via mfma_f32_16x16x32_bf16, bf16x3 (hi/lo split).
__global__ __launch_bounds__(256) void k_cheb_mfma2(
    const unsigned short* __restrict__ Bb, const float* __restrict__ probs,
    const float* __restrict__ ct, const float* __restrict__ Y0,
    const float* __restrict__ sd, int b0, int NFT, float* __restrict__ outX) {
  const int bl = blockIdx.z, b = b0 + bl;
  const int n0 = blockIdx.y * 128;
  const int c0 = blockIdx.x * 128;
  const int tid = threadIdx.x, lane = tid & 63;
  const int wm = (tid >> 7) & 1, wn = (tid >> 6) & 1;
  __shared__ char lds[65536];  // 2 x 32KB: Ahi 8K | Alo 8K | Bhi 8K | Blo 8K
  // ---- staging roles ----
  const int ar = tid >> 1, ahf = tid & 1;          // A: row 0..127, 16-el half
  const int aw0 = ar * 64 + ((((ahf << 1) | 0) ^ (ar & 3)) << 4);
  const int aw1 = ar * 64 + ((((ahf << 1) | 1) ^ (ar & 3)) << 4);
  const int br = tid >> 1, bp = tid & 1;           // B: row 0..127, plane hi/lo
  int brr = c0 + br;
  if (brr >= NFT) brr = 0;                         // clamp: lands in write-masked cols
  const unsigned short* gB = Bb + (size_t)bl * NFT * 2048 + (size_t)bp * NFT * 1024
                                + (size_t)brr * 1024;
  int bw[4];
#pragma unroll
  for (int sl = 0; sl < 4; sl++) bw[sl] = (2 + bp) * 8192 + br * 64 + ((sl ^ (br & 3)) << 4);
  const float* pRow = probs + ((size_t)b * NN + (n0 + ar)) * NN;
  const size_t ctRow = (size_t)(n0 + ar) * NN;
  // ---- frag read offsets (same swizzle as write side) ----
  const int off16 = ((lane >> 4) ^ (lane & 3)) << 4;
  int rA[4], rB[4];
#pragma unroll
  for (int m = 0; m < 4; m++) rA[m] = (wm * 64 + m * 16 + (lane & 15)) * 64 + off16;
#pragma unroll
  for (int j = 0; j < 4; j++) rB[j] = (wn * 64 + j * 16 + (lane & 15)) * 64 + off16 + 16384;
  f32x4 acc[4][4] = {};
  float4 pv[4], cv[4], bv[4];
  auto loadK = [&](int kc) {
    const int pl = kc >> 4;                    // 0 -> k=1 half, 1 -> k=2 half
    const int mb = (kc & 15) * 32 + ahf * 16;  // m within half
    const float* pp = pRow + mb;
    const float* cp = ct + (size_t)(pl + 1) * (NN * NN) + ctRow + mb;
#pragma unroll
    for (int q = 0; q < 4; q++) {
      pv[q] = *(const float4*)(pp + q * 4);
      cv[q] = *(const float4*)(cp + q * 4);
    }
    const unsigned short* bb = gB + kc * 32;
#pragma unroll
    for (int q = 0; q < 4; q++) bv[q] = *(const float4*)(bb + q * 8);
  };
  auto stage = [&](char* base) {
#pragma unroll
    for (int sl = 0; sl < 4; sl++) *(float4*)(base + bw[sl]) = bv[sl];
    float a[16];
#pragma unroll
    for (int q = 0; q < 4; q++) {
      a[q * 4 + 0] = pv[q].x * cv[q].x;
      a[q * 4 + 1] = pv[q].y * cv[q].y;
      a[q * 4 + 2] = pv[q].z * cv[q].z;
      a[q * 4 + 3] = pv[q].w * cv[q].w;
    }
    unsigned int hw[8], lw[8];
#pragma unroll
    for (int q = 0; q < 8; q++) {
      unsigned short h0 = bf16rne(a[q * 2]), h1 = bf16rne(a[q * 2 + 1]);
      hw[q] = (unsigned int)h0 | ((unsigned int)h1 << 16);
      unsigned short l0 = bf16rne(a[q * 2] - bfval(h0));
      unsigned short l1 = bf16rne(a[q * 2 + 1] - bfval(h1));
      lw[q] = (unsigned int)l0 | ((unsigned int)l1 << 16);
    }
    *(uint4*)(base + aw0) = make_uint4(hw[0], hw[1], hw[2], hw[3]);
    *(uint4*)(base + aw1) = make_uint4(hw[4], hw[5], hw[6], hw[7]);
    *(uint4*)(base + 8192 + aw0) = make_uint4(lw[0], lw[1], lw[2], lw[3]);
    *(uint4*)(base + 8192 + aw1) = make_uint4(lw[4], lw[5], lw[6], lw[7]);
  };
  loadK(0);
  stage(lds);
  __syncthreads();
  for (int kc = 0; kc < 32; kc++) {
    char* cur = lds + ((kc & 1) << 15);
    if (kc < 31) loadK(kc + 1);
    bf16x8 ah[4], al[4], bh[4], blr[4];
#pragma unroll
    for (int m = 0; m < 4; m++) {
      ah[m] = *(const bf16x8*)(cur + rA[m]);
      al[m] = *(const bf16x8*)(cur + rA[m] + 8192);
    }
#pragma unroll
    for (int j = 0; j < 4; j++) {
      bh[j] = *(const bf16x8*)(cur + rB[j]);
      blr[j] = *(const bf16x8*)(cur + rB[j] + 8192);
    }
#pragma unroll
    for (int m = 0; m < 4; m++)
#pragma unroll
      for (int j = 0; j < 4; j++) {
        acc[m][j] = __builtin_amdgcn_mfma_f32_16x16x32_bf16(ah[m], bh[j], acc[m][j], 0, 0, 0);
        acc[m][j] = __builtin_amdgcn_mfma_f32_16x16x32_bf16(al[m], bh[j], acc[m][j], 0, 0, 0);
        acc[m][j] = __builtin_amdgcn_mfma_f32_16x16x32_bf16(ah[m], blr[j], acc[m][j], 0, 0, 0);
      }
    if (kc < 31) stage(lds + (((kc & 1) ^ 1) << 15));
    __syncthreads();
  }
#pragma unroll
  for (int m = 0; m < 4; m++) {
    const int nb = n0 + wm * 64 + m * 16 + (lane >> 4) * 4;
#pragma unroll
    for (int j = 0; j < 4; j++) {
      const int c = c0 + wn * 64 + j * 16 + (lane & 15);
      if (c < NFT) {
        const float* Yc = Y0 + ((size_t)bl * NFT + c) * NN;
#pragma unroll
        for (int rg = 0; rg < 4; rg++) {
          const int n = nb + rg;
          if (n < NN) {
            float v = acc[m][j][rg] + sd[(size_t)b * NN + n] * Yc[n];
            outX[((size_t)b * NN + n) * NFT + c] = fmaxf(v, 0.f);
          }
        }
      }
    }
  }
}

// ---- layer norm over (C,N,T) per sample; one block per b ----
__global__ __launch_bounds__(256) void k_ln_stat(const float* x, float* stat, int M) {
  int b = blockIdx.x;
  const float* xp = x + (size_t)b * M;
  float s1 = 0.f, s2 = 0.f;
  for (int i = threadIdx.x; i < M; i += 256) {
    float v = xp[i]; s1 += v; s2 += v * v;
  }
  __shared__ float r1[256], r2[256];
  int tid = threadIdx.x;
  r1[tid] = s1; r2[tid] = s2;
  __syncthreads();
  for (int s = 128; s > 0; s >>= 1) {
    if (tid < s) { r1[tid] += r1[tid + s]; r2[tid] += r2[tid + s]; }
    __syncthreads();
  }
  if (tid == 0) {
    float mean = r1[0] / M;
    float var = r2[0] / M - mean * mean;
    stat[b * 2] = mean;
    stat[b * 2 + 1] = rsqrtf(var + 1e-5f);
  }
}
__global__ void k_ln_norm(const float* x, const float* stat, const float* wn, const float* bn,
                          float* out, int M) {
  int total = NB * M;
  int idx = blockIdx.x * 256 + threadIdx.x;
  if (idx >= total) return;
  int b = idx / M;
  int i = idx % M;
  float y = (x[idx] - stat[b * 2]) * stat[b * 2 + 1];
  out[idx] = y * wn[i] + bn[i];
}

// ---- final head ----
__global__ void k_fin1(const float* h, const float* w, const float* bias, const float* skip,
                       float* out) {
  int total = NB * 64 * NN;
  int idx = blockIdx.x * 256 + threadIdx.x;
  if (idx >= total) return;
  int n = idx % NN;
  int c = (idx / NN) % 64;
  int b = idx / (NN * 64);
  float v = bias[c];
  for (int ci = 0; ci < 32; ci++) v += w[c * 32 + ci] * h[(b * NF + ci) * NN + n];
  v += skip[((size_t)(b * 64 + c) * NN + n) * 7 + 6];
  out[idx] = fmaxf(v, 0.f);
}
__global__ void k_fin2(const float* in, const float* w, const float* bias, float* out) {
  int total = NB * 128 * NN;
  int idx = blockIdx.x * 256 + threadIdx.x;
  if (idx >= total) return;
  int n = idx % NN;
  int c = (idx / NN) % 128;
  int b = idx / (NN * 128);
  float v = bias[c];
  for (int ci = 0; ci < 64; ci++) v += w[c * 64 + ci] * in[(b * 64 + ci) * NN + n];
  out[idx] = fmaxf(v, 0.f);
}
__global__ void k_fin3(const float* in, const float* w, const float* bias, float* out) {
  int total = NB * 12 * NN;
  int idx = blockIdx.x * 256 + threadIdx.x;
  if (idx >= total) return;
  int n = idx % NN;
  int c = (idx / NN) % 12;
  int b = idx / (NN * 12);
  float v = bias[c];
  for (int ci = 0; ci < 128; ci++) v += w[c * 128 + ci] * in[(b * 128 + ci) * NN + n];
  out[idx] = v;
}

#define G1(tot) dim3((unsigned)(((tot) + 255) / 256)), dim3(256), 0, stream

extern "C" void kernel_launch(void* const* d_in, const int* in_sizes, int n_in,
                              void* d_out, int out_size, void* d_ws, size_t ws_size,
                              hipStream_t stream) {
  (void)in_sizes; (void)n_in; (void)out_size; (void)ws_size;
  auto I = [&](int i) { return (const float*)d_in[i]; };
  float* W = (float*)d_ws;
  size_t off = 0;
  auto alloc = [&](size_t nel) { float* p = W + off; off += nel; return p; };

  float* bufA  = alloc(9728000);   // h / residual [B,32,N,19max]
  float* bufB  = alloc(9728000);   // h after fc1; later cheb output (t-major, in place)
  float* bufC  = alloc(9728000);   // x_tat -> s1T -> probs (in-place softmax)
  float* bufSK = alloc(7168000);   // skip [B,64,N,7]
  float* skip0 = alloc(1024000);   // skip [B,64,N,1]; dead after layer-0 skipconv
  float* P1    = alloc(9728000);   // s0; dead after k_gemm_vs (within each layer)
  float* CT    = alloc(750000);    // chebT
  float* VST   = alloc(250000);    // vs transposed (per layer)
  float* TL1   = alloc(19456);
  float* TLH   = alloc(304000);
  float* TRH   = alloc(304000);
  float* TE    = alloc(11552);
  float* TE0   = alloc(11552);     // e0 intermediate
  float* SL1   = alloc(512000);
  float* SLH   = alloc(304000);
  float* SRH   = alloc(304000);
  float* ACC   = alloc(64);
  float* SD    = alloc(16000);     // sd[b][n] = p[b,n,n]
  float* THT   = alloc(3072);      // thetaT[k][f2][f]

  // cheb staging: reuse skip0+P1 (contiguous 10,752,000 floats, dead at cheb time).
  constexpr int GB = 11;
  float* STG = skip0;
  unsigned short* Bb = (unsigned short*)STG;   // [bl][2][NFT][1024] bf16
  float* Y0f = STG + 6848512;                  // [bl][NFT][500] fp32

  float* P2 = bufC;                // s1T/probs live in bufC through the cheb GEMM
  float* F1 = P1;                  // [B,64,N] final head, after staging is dead
  float* F2 = P1 + 1024000;        // [B,128,N]

  k_start<<<G1(NB * NF * NN * 19)>>>(I(0), I(1), I(2), bufA);
  k_skip0<<<G1(NB * 64 * NN)>>>(I(0), I(3), I(4), skip0);
  k_chebT<<<G1(3 * NN * NN)>>>(I(59), CT);
  k_thetaT<<<G1(3 * NF * NF)>>>(I(60), THT);

  dim3 ggt((NN + 7) / 8, NB), bgt(256);
  auto gtufc = [&](int Ti, int To, const float* hin, const float* fw, const float* fb,
                   const float* res, float* o) {
    if (Ti == 19 && To == 19)
      k_gtufc_t<19, 19><<<ggt, bgt, 0, stream>>>(hin, I(5), I(6), I(7), I(8), I(9), I(10), fw, fb, res, o);
    else if (Ti == 13 && To == 13)
      k_gtufc_t<13, 13><<<ggt, bgt, 0, stream>>>(hin, I(5), I(6), I(7), I(8), I(9), I(10), fw, fb, res, o);
    else
      k_gtufc_t<7, 7><<<ggt, bgt, 0, stream>>>(hin, I(5), I(6), I(7), I(8), I(9), I(10), fw, fb, res, o);
  };
  auto gtufcx = [&](int Ti, int To, const float* hin, const float* fw, const float* fb,
                    const float* res, float* o) {
    if (Ti == 19)
      k_gtufc_x<19, 13><<<ggt, bgt, 0, stream>>>(hin, I(5), I(6), I(7), I(8), I(9), I(10), fw, fb, res, o);
    else if (Ti == 13)
      k_gtufc_x<13, 7><<<ggt, bgt, 0, stream>>>(hin, I(5), I(6), I(7), I(8), I(9), I(10), fw, fb, res, o);
    else
      k_gtufc_x<7, 1><<<ggt, bgt, 0, stream>>>(hin, I(5), I(6), I(7), I(8), I(9), I(10), fw, fb, res, o);
  };

  const int Tin[3] = {19, 13, 7}, Tout[3] = {13, 7, 1};
  for (int i = 0; i < 3; i++) {
    int Ti = Tin[i], To = Tout[i];
    // gated TCN + fc1 + relu-add : bufA -> bufB
    gtufc(Ti, Ti, bufA, I(11 + 2 * i), I(12 + 2 * i), nullptr, bufB);
    // skip conv
    if (i == 0)
      k_skipconv_t<19, 13><<<ggt, bgt, 0, stream>>>(bufB, I(23), I(24), skip0, 1, bufSK);
    else if (i == 1)
      k_skipconv_t<13, 7><<<ggt, bgt, 0, stream>>>(bufB, I(25), I(26), bufSK, 7, bufSK);
    else
      k_skipconv_t<7, 1><<<ggt, bgt, 0, stream>>>(bufB, I(27), I(28), bufSK, 7, bufSK);
    // temporal attention
    int ba = 29 + i * 10;
    k_zero<<<G1(NB * Ti * NF)>>>(TL1, NB * Ti * NF);
    k_ta_lhs1b<<<dim3(20, NB), dim3(256), 0, stream>>>(bufB, I(ba + 0), TL1, Ti);
    k_ta_lhs<<<G1(NB * Ti * NN)>>>(TL1, I(ba + 1), TLH, Ti);
    k_ta_rhs<<<G1(NB * NN * Ti)>>>(bufB, I(ba + 2), TRH, Ti);
    k_ta_e0<<<dim3(Ti, NB), dim3(256), 0, stream>>>(TLH, TRH, I(ba + 3), TE0, Ti);
    k_ta_att2<<<dim3(NB), dim3(256), 0, stream>>>(TE0, I(ba + 4), TE, Ti);
    k_xtat<<<G1(NB * NF * NN * Ti)>>>(TE, bufB, bufC, Ti);  // x_tat into bufC
    // spatial attention
    k_sa_lhs1<<<G1(NB * NN * NF)>>>(bufC, I(ba + 5), SL1, Ti);
    k_sa_lhs<<<G1(NB * NN * Ti)>>>(SL1, I(ba + 6), SLH, Ti);
    k_sa_rhs<<<G1(NB * Ti * NN)>>>(bufC, I(ba + 7), SRH, Ti);
    k_sa_prod<<<G1(NB * NN * NN)>>>(SLH, SRH, I(ba + 8), P1, Ti);  // x_tat consumed
    k_transpose<<<dim3(16, 16), dim3(256), 0, stream>>>(I(ba + 9), VST);
    {
      dim3 gg((NN + 127) / 128, 8, NB);
      k_gemm_vs<<<gg, dim3(256), 0, stream>>>(VST, P1, P2);  // s1T into bufC; P1 free
    }
    // ==== cheb conv via bf16x3 MFMA: in-place softmax + on-the-fly A + b-groups ====
    int NFT = NF * Ti;
    k_smax_ip<<<dim3(NN, NB), dim3(256), 0, stream>>>(P2, SD);  // probs in place in bufC
    for (int b0 = 0; b0 < NB; b0 += GB) {
      int gsz = (NB - b0 < GB) ? (NB - b0) : GB;
      k_prepY2<<<dim3(Ti, gsz), dim3(256), 0, stream>>>(bufB, THT, Ti, b0, Bb, Y0f);
      dim3 gm((NFT + 127) / 128, 4, gsz);
      k_cheb_mfma2<<<gm, dim3(256), 0, stream>>>(Bb, P2, CT, Y0f, SD, b0, NFT, bufB);
    }
    // second gated TCN (t-major input) + fc2 + relu-add + residual : bufB (+bufA) -> bufC
    gtufcx(Ti, To, bufB, I(17 + 2 * i), I(18 + 2 * i), bufA, bufC);
    // layer norm: bufC -> bufA
    int M = NF * NN * To;
    k_ln_stat<<<dim3(NB), dim3(256), 0, stream>>>(bufC, ACC, M);
    k_ln_norm<<<G1(NB * M)>>>(bufC, ACC, I(61 + 2 * i), I(62 + 2 * i), bufA, M);
  }
  // final head
  k_fin1<<<G1(NB * 64 * NN)>>>(bufA, I(67), I(68), bufSK, F1);
  k_fin2<<<G1(NB * 128 * NN)>>>(F1, I(69), I(70), F2);
  k_fin3<<<G1(NB * 12 * NN)>>>(F2, I(71), I(72), (float*)d_out);
}

// Round 7
// 4857.861 us; speedup vs baseline: 1.2930x; 1.1721x over previous
//
#include <hip/hip_runtime.h>
#include <hip/hip_bf16.h>
#include <math.h>

#define NB 32      // batch
#define NN 500     // nodes
#define NF 32      // channels

typedef float f32x4 __attribute__((ext_vector_type(4)));
typedef short bf16x8 __attribute__((ext_vector_type(8)));

__device__ __forceinline__ float sigf(float x) { return 1.0f / (1.0f + __expf(-x)); }
// fast tanh: |err| ~1e-7, no overflow (e in (0,1])
__device__ __forceinline__ float tanhf_fast(float x) {
  float e = __expf(-2.0f * fabsf(x));
  float r = (1.0f - e) / (1.0f + e);
  return copysignf(r, x);
}

__device__ __forceinline__ unsigned short bf16rne(float x) {
  unsigned int u = __float_as_uint(x);
  unsigned int r = u + 0x7FFFu + ((u >> 16) & 1u);
  return (unsigned short)(r >> 16);
}
__device__ __forceinline__ float bfval(unsigned short h) {
  return __uint_as_float((unsigned int)h << 16);
}

__global__ void k_zero(float* p, int n) {
  int i = blockIdx.x * 256 + threadIdx.x;
  if (i < n) p[i] = 0.f;
}

// h[b,c,n,t] = b_start[c] + sum_ci w_start[c,ci]*padded_x[b,ci,n,t]; pad 7 zeros at front (19)
__global__ void k_start(const float* x, const float* w, const float* bias, float* h) {
  int idx = blockIdx.x * 256 + threadIdx.x;
  const int total = NB * NF * NN * 19;
  if (idx >= total) return;
  int t = idx % 19;
  int n = (idx / 19) % NN;
  int c = (idx / (19 * NN)) % NF;
  int b = idx / (19 * NN * NF);
  float v = bias[c];
  if (t >= 7) {
    int tx = t - 7;
    v += w[c * 2 + 0] * x[((size_t)(b * 2 + 0) * NN + n) * 12 + tx];
    v += w[c * 2 + 1] * x[((size_t)(b * 2 + 1) * NN + n) * 12 + tx];
  }
  h[idx] = v;
}

// skip0[b,c,n] = b_sk0[c] + sum_{ci,k>=7} w_sk0[c,ci,k]*x[b,ci,n,k-7]
__global__ void k_skip0(const float* x, const float* w, const float* bias, float* s0) {
  int idx = blockIdx.x * 256 + threadIdx.x;
  const int total = NB * 64 * NN;
  if (idx >= total) return;
  int n = idx % NN;
  int c = (idx / NN) % 64;
  int b = idx / (NN * 64);
  float v = bias[c];
  for (int ci = 0; ci < 2; ci++)
    for (int k = 7; k < 19; k++)
      v += w[(c * 2 + ci) * 19 + k] * x[((size_t)(b * 2 + ci) * NN + n) * 12 + (k - 7)];
  s0[idx] = v;
}

// ==== MFMA gated-TCN + fc ====
// Pack conv weights into bf16 hi/lo A-fragment planes:
// WP[sj*4096 + plane*2048 + o*32 + ci], sj: s0 j0-2 -> 0..2, s1 j0-4 -> 3..7, s2 j0-6 -> 8..14
__global__ void k_packW(const float* wg3, const float* wg5, const float* wg7,
                        unsigned short* WP) {
  int idx = blockIdx.x * 256 + threadIdx.x;
  if (idx >= 15 * 2048) return;
  int sj = idx >> 11, r = idx & 2047;
  int o = r >> 5, ci = r & 31;
  const float* src; int K, j;
  if (sj < 3)      { src = wg3; K = 3; j = sj; }
  else if (sj < 8) { src = wg5; K = 5; j = sj - 3; }
  else             { src = wg7; K = 7; j = sj - 8; }
  float v = src[(o * 32 + ci) * K + j];
  unsigned short hi = bf16rne(v);
  WP[sj * 4096 + r] = hi;
  WP[sj * 4096 + 2048 + r] = bf16rne(v - bfval(hi));
}

// One conv segment as sum of shifted K=32 GEMMs; gate epilogue -> tcb[(o*8+nl)*Ls + t].
template<int TI, int TPP, int Ks, int Ls>
__device__ __forceinline__ void seg_pass(
    const unsigned short* __restrict__ WPs, const float* __restrict__ bg,
    const unsigned short* hsh, const unsigned short* hsl, float* tcb,
    int lane, int w) {
  constexpr int NT = (8 * TPP) / 16;
  const int r16 = lane & 15, q4 = lane >> 4;
  const int k0 = q4 << 3;
  for (int tile = w; tile < NT; tile += 4) {
    f32x4 acc[4] = {};
    const int bcol = tile * 16 + r16;
#pragma unroll
    for (int j = 0; j < Ks; j++) {
      bf16x8 bh = *(const bf16x8*)&hsh[(bcol + j) * 32 + k0];
      bf16x8 bl = *(const bf16x8*)&hsl[(bcol + j) * 32 + k0];
#pragma unroll
      for (int m = 0; m < 4; m++) {
        const unsigned short* ap = WPs + (size_t)j * 4096 + (m * 16 + r16) * 32 + k0;
        bf16x8 ah = *(const bf16x8*)ap;
        bf16x8 al = *(const bf16x8*)(ap + 2048);
        acc[m] = __builtin_amdgcn_mfma_f32_16x16x32_bf16(ah, bh, acc[m], 0, 0, 0);
        acc[m] = __builtin_amdgcn_mfma_f32_16x16x32_bf16(al, bh, acc[m], 0, 0, 0);
        acc[m] = __builtin_amdgcn_mfma_f32_16x16x32_bf16(ah, bl, acc[m], 0, 0, 0);
      }
    }
    const int col = tile * 16 + r16;
    const int nl = col / TPP, tt = col - nl * TPP;
    if (tt < Ls) {
#pragma unroll
      for (int m = 0; m < 2; m++)
#pragma unroll
        for (int rg = 0; rg < 4; rg++) {
          const int o = m * 16 + (q4 << 2) + rg;
          float tcv = tanhf_fast(acc[m][rg] + bg[o]) * sigf(acc[m + 2][rg] + bg[o + 32]);
          tcb[(o * 8 + nl) * Ls + tt] = tcv;
        }
    }
  }
}

// Fused gated-TCN (3 segs) + fc + relu-add (+res). XL: t-major input hX[b][n][t*NF+f].
template<int TI, int TO, bool XL>
__global__ __launch_bounds__(256) void k_gtu_mfma(
    const float* __restrict__ hin, const unsigned short* __restrict__ WP,
    const float* __restrict__ bg3, const float* __restrict__ bg5, const float* __restrict__ bg7,
    const float* __restrict__ fw, const float* __restrict__ fb,
    const float* __restrict__ res, float* __restrict__ out) {
  constexpr int TPP = (TI + 3) & ~3;   // 20 / 16 / 8
  constexpr int TCAT = 3 * TI - 12;
  constexpr int OFF = TI - TO;
  constexpr int NFT = NF * TI;
  constexpr int EP = (8 * TPP + 16) * 32;
  constexpr int LMAX = TI - 2;
  __shared__ __align__(16) char smem[EP * 4 + 32 * 8 * LMAX * 4];
  unsigned short* hsh = (unsigned short*)smem;
  unsigned short* hsl = hsh + EP;
  float* tcb = (float*)(smem + EP * 4);
  const int b = blockIdx.y, n0 = blockIdx.x * 8;
  const int tid = threadIdx.x, lane = tid & 63, w = tid >> 6;
  for (int l = tid; l < EP; l += 256) { hsh[l] = 0; hsl[l] = 0; }
  __syncthreads();
  if (XL) {
    for (int l = tid; l < 8 * NFT; l += 256) {
      int nl = l / NFT, r = l - nl * NFT;
      int n = n0 + nl;
      if (n < NN) {
        float v = hin[(size_t)(b * NN + n) * NFT + r];
        int col = nl * TPP + (r >> 5);
        unsigned short hi = bf16rne(v);
        hsh[col * 32 + (r & 31)] = hi;
        hsl[col * 32 + (r & 31)] = bf16rne(v - bfval(hi));
      }
    }
  } else {
    for (int l = tid; l < 8 * NF * TI; l += 256) {
      int t = l % TI, ci = (l / TI) & 31, nl = l / (TI * NF);
      int n = n0 + nl;
      if (n < NN) {
        float v = hin[((size_t)(b * NF + ci) * NN + n) * TI + t];
        int col = nl * TPP + t;
        unsigned short hi = bf16rne(v);
        hsh[col * 32 + ci] = hi;
        hsl[col * 32 + ci] = bf16rne(v - bfval(hi));
      }
    }
  }
  __syncthreads();
  const int c = tid & 31, nl2 = tid >> 5;
  const int n = n0 + nl2;
  float oacc[TO];
#pragma unroll
  for (int o = 0; o < TO; o++) oacc[o] = 0.f;
  // seg 0 (K=3)
  seg_pass<TI, TPP, 3, TI - 2>(WP, bg3, hsh, hsl, tcb, lane, w);
  __syncthreads();
  if (n < NN) {
    const float* tp = &tcb[(c * 8 + nl2) * (TI - 2)];
    for (int t = 0; t < TI - 2; t++) {
      float tv = tp[t];
#pragma unroll
      for (int o = 0; o < TO; o++) oacc[o] += tv * fw[o * TCAT + t];
    }
  }
  __syncthreads();
  // seg 1 (K=5)
  seg_pass<TI, TPP, 5, TI - 4>(WP + 3 * 4096, bg5, hsh, hsl, tcb, lane, w);
  __syncthreads();
  if (n < NN) {
    const float* tp = &tcb[(c * 8 + nl2) * (TI - 4)];
    for (int t = 0; t < TI - 4; t++) {
      float tv = tp[t];
#pragma unroll
      for (int o = 0; o < TO; o++) oacc[o] += tv * fw[o * TCAT + (TI - 2) + t];
    }
  }
  __syncthreads();
  // seg 2 (K=7)
  seg_pass<TI, TPP, 7, TI - 6>(WP + 8 * 4096, bg7, hsh, hsl, tcb, lane, w);
  __syncthreads();
  if (n < NN) {
    const float* tp = &tcb[(c * 8 + nl2) * (TI - 6)];
    for (int t = 0; t < TI - 6; t++) {
      float tv = tp[t];
#pragma unroll
      for (int o = 0; o < TO; o++) oacc[o] += tv * fw[o * TCAT + (2 * TI - 6) + t];
    }
    size_t base = (size_t)(b * NF + c) * NN + n;
#pragma unroll
    for (int o = 0; o < TO; o++) {
      float self = XL ? hin[(size_t)(b * NN + n) * NFT + (OFF + o) * NF + c]
                      : hin[base * TI + OFF + o];
      float v = fmaxf(self + oacc[o] + fb[o], 0.f);
      if (res) v += res[base * TI + OFF + o];
      out[base * TO + o] = v;
    }
  }
}

// ---- skip conv, LDS h staging, weights in registers, K unrolled ----
template<int TI, int K>
__global__ __launch_bounds__(256) void k_skipconv_t(
    const float* __restrict__ h, const float* __restrict__ w,
    const float* __restrict__ bias, const float* __restrict__ prev, int prevT,
    float* __restrict__ out) {
  constexpr int TP = (TI + 3) & ~3;
  const int b = blockIdx.y, n0 = blockIdx.x * 8, tid = threadIdx.x;
  __shared__ float hs[8 * NF * TP];
  for (int l = tid; l < 8 * NF * TP; l += 256) {
    int t = l % TP;
    int ci = (l / TP) % NF;
    int n2 = l / (TP * NF);
    int gn = n0 + n2;
    hs[l] = (t < TI && gn < NN) ? h[((size_t)(b * NF + ci) * NN + gn) * TI + t] : 0.f;
  }
  __syncthreads();
  const int c = tid & 63, ng = tid >> 6;
  float bv = bias[c];
  float o[2][7];
#pragma unroll
  for (int q = 0; q < 2; q++)
#pragma unroll
    for (int t = 0; t < 7; t++) o[q][t] = bv;
  for (int ci = 0; ci < NF; ci++) {
    float wv[K];
#pragma unroll
    for (int j = 0; j < K; j++) wv[j] = w[(c * NF + ci) * K + j];
#pragma unroll
    for (int q = 0; q < 2; q++) {
      const float* hp = hs + ((ng + q * 4) * NF + ci) * TP;
      float hl[6 + K];
#pragma unroll
      for (int t = 0; t < 6 + K; t++) hl[t] = hp[t];
#pragma unroll
      for (int j = 0; j < K; j++)
#pragma unroll
        for (int t = 0; t < 7; t++) o[q][t] += wv[j] * hl[t + j];
    }
  }
#pragma unroll
  for (int q = 0; q < 2; q++) {
    int n = n0 + ng + q * 4;
    if (n < NN) {
      size_t base = (size_t)(b * 64 + c) * NN + n;
#pragma unroll
      for (int t = 0; t < 7; t++) {
        float pv = (prevT == 1) ? prev[base] : prev[base * 7 + t];
        out[base * 7 + t] = o[q][t] + pv;
      }
    }
  }
}

// ---- temporal attention ----
__global__ __launch_bounds__(256) void k_ta_lhs1b(const float* __restrict__ h,
                                                  const float* __restrict__ u1,
                                                  float* __restrict__ out, int T) {
  const int ch = blockIdx.x, b = blockIdx.y;
  const int n0 = ch * 25;
  const int tid = threadIdx.x;
  __shared__ float hs[25 * NF * 19];  // [n][f][t]
  const int tot = 25 * NF * T;
  for (int l = tid; l < tot; l += 256) {
    int t = l % T;
    int f = (l / T) % NF;
    int n2 = l / (T * NF);
    hs[(n2 * NF + f) * T + t] = h[((size_t)(b * NF + f) * NN + n0 + n2) * T + t];
  }
  __syncthreads();
  for (int l2 = tid; l2 < NF * T; l2 += 256) {
    int f = l2 / T, t = l2 % T;
    float acc = 0.f;
#pragma unroll 5
    for (int n2 = 0; n2 < 25; n2++)
      acc += hs[(n2 * NF + f) * T + t] * u1[n0 + n2];
    atomicAdd(&out[(b * T + t) * NF + f], acc);
  }
}
__global__ void k_ta_lhs(const float* l1, const float* u2, float* out, int T) {
  int total = NB * T * NN;
  int idx = blockIdx.x * 256 + threadIdx.x;
  if (idx >= total) return;
  int n = idx % NN;
  int t = (idx / NN) % T;
  int b = idx / (NN * T);
  float acc = 0.f;
  for (int f = 0; f < NF; f++) acc += l1[(b * T + t) * NF + f] * u2[f * NN + n];
  out[idx] = acc;  // (b,t,n)
}
__global__ void k_ta_rhs(const float* h, const float* u3, float* out, int T) {
  int total = NB * NN * T;
  int idx = blockIdx.x * 256 + threadIdx.x;
  if (idx >= total) return;
  int t = idx % T;
  int n = (idx / T) % NN;
  int b = idx / (T * NN);
  float acc = 0.f;
  for (int f = 0; f < NF; f++) acc += u3[f] * h[((size_t)(b * NF + f) * NN + n) * T + t];
  out[idx] = acc;  // (b,n,t)
}
__global__ __launch_bounds__(256) void k_ta_e0(const float* __restrict__ lhs,
                                               const float* __restrict__ rhs,
                                               const float* __restrict__ be,
                                               float* __restrict__ e0g, int T) {
  const int t = blockIdx.x, b = blockIdx.y, tid = threadIdx.x;
  const float* lp = lhs + ((size_t)b * T + t) * NN;
  const float* rp = rhs + (size_t)b * NN * T;
  float acc[19];
#pragma unroll
  for (int m = 0; m < 19; m++) acc[m] = 0.f;
  for (int n = tid; n < NN; n += 256) {
    float lv = lp[n];
    const float* rr = rp + (size_t)n * T;
    for (int m = 0; m < T; m++) acc[m] += lv * rr[m];
  }
  __shared__ float red[256 * 20];
  for (int m = 0; m < T; m++) red[tid * 20 + m] = acc[m];
  __syncthreads();
  for (int s = 128; s > 0; s >>= 1) {
    if (tid < s)
      for (int m = 0; m < T; m++) red[tid * 20 + m] += red[(tid + s) * 20 + m];
    __syncthreads();
  }
  if (tid < T)
    e0g[((size_t)b * T + t) * T + tid] = sigf(red[tid] + be[t * T + tid]);
}
__global__ __launch_bounds__(256) void k_ta_att2(const float* __restrict__ e0g,
                                                 const float* __restrict__ ve,
                                                 float* __restrict__ e, int T) {
  int b = blockIdx.x, tid = threadIdx.x;
  __shared__ float e0[19 * 19];
  __shared__ float e1[19 * 19];
  int TT = T * T;
  for (int l = tid; l < TT; l += 256) e0[l] = e0g[(size_t)b * TT + l];
  __syncthreads();
  for (int l = tid; l < TT; l += 256) {
    int t = l / T, m = l % T;
    float acc = 0.f;
    for (int j = 0; j < T; j++) acc += ve[t * T + j] * e0[j * T + m];
    e1[l] = acc;
  }
  __syncthreads();
  if (tid < T) {
    int m = tid;
    float mx = -1e30f;
    for (int t = 0; t < T; t++) mx = fmaxf(mx, e1[t * T + m]);
    float s = 0.f;
    for (int t = 0; t < T; t++) s += __expf(e1[t * T + m] - mx);
    float inv = 1.f / s;
    for (int t = 0; t < T; t++)
      e[((size_t)b * T + t) * T + m] = __expf(e1[t * T + m] - mx) * inv;
  }
}
__global__ void k_xtat(const float* e, const float* h, float* xt, int T) {
  int total = NB * NF * NN * T;
  int idx = blockIdx.x * 256 + threadIdx.x;
  if (idx >= total) return;
  int t = idx % T;
  int n = (idx / T) % NN;
  int f = (idx / (T * NN)) % NF;
  int b = idx / (T * NN * NF);
  const float* hp = h + ((size_t)(b * NF + f) * NN + n) * T;
  float acc = 0.f;
  for (int j = 0; j < T; j++) acc += e[(b * T + t) * T + j] * hp[j];
  xt[idx] = acc;
}

// ---- spatial attention ----
__global__ void k_sa_lhs1(const float* xt, const float* w1, float* out, int T) {
  int total = NB * NN * NF;
  int idx = blockIdx.x * 256 + threadIdx.x;
  if (idx >= total) return;
  int f = idx % NF;
  int n = (idx / NF) % NN;
  int b = idx / (NF * NN);
  const float* xp = xt + ((size_t)(b * NF + f) * NN + n) * T;
  float acc = 0.f;
  for (int t = 0; t < T; t++) acc += xp[t] * w1[t];
  out[(b * NN + n) * NF + f] = acc;
}
__global__ void k_sa_lhs(const float* l1, const float* w2, float* out, int T) {
  int total = NB * NN * T;
  int idx = blockIdx.x * 256 + threadIdx.x;
  if (idx >= total) return;
  int t = idx % T;
  int n = (idx / T) % NN;
  int b = idx / (T * NN);
  float acc = 0.f;
  for (int f = 0; f < NF; f++) acc += l1[(b * NN + n) * NF + f] * w2[f * T + t];
  out[idx] = acc;  // (b,n,t)
}
__global__ void k_sa_rhs(const float* xt, const float* w3, float* out, int T) {
  int total = NB * T * NN;
  int idx = blockIdx.x * 256 + threadIdx.x;
  if (idx >= total) return;
  int n = idx % NN;
  int t = (idx / NN) % T;
  int b = idx / (NN * T);
  float acc = 0.f;
  for (int f = 0; f < NF; f++) acc += w3[f] * xt[((size_t)(b * NF + f) * NN + n) * T + t];
  out[idx] = acc;  // (b,t,n)
}
__global__ void k_sa_prod(const float* lhs, const float* rhs, const float* bs, float* s0, int T) {
  int total = NB * NN * NN;
  int idx = blockIdx.x * 256 + threadIdx.x;
  if (idx >= total) return;
  int m = idx % NN;
  int n = (idx / NN) % NN;
  int b = idx / (NN * NN);
  float acc = 0.f;
  for (int t = 0; t < T; t++)
    acc += lhs[((size_t)b * NN + n) * T + t] * rhs[((size_t)b * T + t) * NN + m];
  s0[idx] = sigf(acc + bs[(size_t)n * NN + m]);
}

// 500x500 transpose (for vs)
__global__ __launch_bounds__(256) void k_transpose(const float* in, float* outT) {
  __shared__ float tile[32][33];
  int x0 = blockIdx.x * 32, y0 = blockIdx.y * 32;
  int tx = threadIdx.x & 31, ty8 = threadIdx.x >> 5;
  for (int yy = ty8; yy < 32; yy += 8) {
    int x = x0 + tx, y = y0 + yy;
    tile[yy][tx] = (x < NN && y < NN) ? in[(size_t)y * NN + x] : 0.f;
  }
  __syncthreads();
  for (int yy = ty8; yy < 32; yy += 8) {
    int x = y0 + tx, y = x0 + yy;
    if (x < NN && y < NN) outT[(size_t)y * NN + x] = tile[tx][yy];
  }
}

// s1T[b,c,r] = (vs @ s0[b])[r,c] — 64x128 tile, double-buffered, float4 everywhere
__global__ __launch_bounds__(256) void k_gemm_vs(const float* __restrict__ vsT,
                                                 const float* __restrict__ s0,
                                                 float* __restrict__ s1t) {
  const int b = blockIdx.z;
  const int row0 = blockIdx.y * 64, col0 = blockIdx.x * 128;
  const int tid = threadIdx.x;
  const int tx = tid & 15, ty = tid >> 4;
  __shared__ float smem[6400];      // 2 x (As 16x68 + Bs 16x132)
  float acc[4][8] = {};
  const float* S0 = s0 + (size_t)b * NN * NN;
  const int nch = (NN + 15) / 16;
  float4 pa, pb0, pb1;
  auto loadregs = [&](int k0) {
    {
      int rq = tid & 15, kk = tid >> 4;
      int gk = k0 + kk, gi = row0 + rq * 4;
      float4 v = {0.f, 0.f, 0.f, 0.f};
      if (gk < NN && gi < NN) v = *(const float4*)&vsT[(size_t)gk * NN + gi];
      pa = v;
    }
#pragma unroll
    for (int it = 0; it < 2; it++) {
      int l = tid + it * 256;
      int q = l & 31, kk = l >> 5;
      int gk = k0 + kk, gc = col0 + q * 4;
      float4 v = {0.f, 0.f, 0.f, 0.f};
      if (gk < NN && gc < NN) v = *(const float4*)&S0[(size_t)gk * NN + gc];
      if (it == 0) pb0 = v; else pb1 = v;
    }
  };
  auto writebuf = [&](int buf) {
    float* As = smem + buf * 3200;
    float* Bs = As + 1088;
    {
      int rq = tid & 15, kk = tid >> 4;
      *(float4*)&As[kk * 68 + rq * 4] = pa;
    }
#pragma unroll
    for (int it = 0; it < 2; it++) {
      int l = tid + it * 256;
      int q = l & 31, kk = l >> 5;
      *(float4*)&Bs[kk * 132 + q * 4] = (it == 0) ? pb0 : pb1;
    }
  };
  loadregs(0);
  writebuf(0);
  for (int ch = 0; ch < nch; ch++) {
    int cur = ch & 1;
    if (ch + 1 < nch) loadregs((ch + 1) * 16);
    __syncthreads();
    const float* As = smem + cur * 3200;
    const float* Bs = As + 1088;
#pragma unroll
    for (int kk = 0; kk < 16; kk++) {
      float4 a4 = *(const float4*)&As[kk * 68 + ty * 4];
      float4 b0 = *(const float4*)&Bs[kk * 132 + tx * 4];
      float4 b1 = *(const float4*)&Bs[kk * 132 + 64 + tx * 4];
      float a[4] = {a4.x, a4.y, a4.z, a4.w};
      float bb[8] = {b0.x, b0.y, b0.z, b0.w, b1.x, b1.y, b1.z, b1.w};
#pragma unroll
      for (int i = 0; i < 4; i++)
#pragma unroll
        for (int j = 0; j < 8; j++) acc[i][j] += a[i] * bb[j];
    }
    if (ch + 1 < nch) writebuf((ch + 1) & 1);
  }
  float* S1 = s1t + (size_t)b * NN * NN;
  int gi0 = row0 + ty * 4;
  if (gi0 < NN) {  // NN%4==0 so gi0<NN implies gi0+3<NN
#pragma unroll
    for (int j = 0; j < 8; j++) {
      int gc = col0 + (j < 4 ? tx * 4 + j : 64 + tx * 4 + (j - 4));
      if (gc < NN) {
        float4 v = {acc[0][j], acc[1][j], acc[2][j], acc[3][j]};
        *(float4*)&S1[(size_t)gc * NN + gi0] = v;
      }
    }
  }
}

// chebT[k,n,m] = cheb[k,m,n]
__global__ void k_chebT(const float* cheb, float* ct) {
  int total = 3 * NN * NN;
  int idx = blockIdx.x * 256 + threadIdx.x;
  if (idx >= total) return;
  int m = idx % NN;
  int n = (idx / NN) % NN;
  int k = idx / (NN * NN);
  ct[idx] = cheb[((size_t)k * NN + m) * NN + n];
}

// thetaT[k][f2][f] = theta[k][f][f2] (for vector-load access in k_prepY2)
__global__ void k_thetaT(const float* theta, float* tht) {
  int idx = blockIdx.x * 256 + threadIdx.x;
  if (idx >= 3 * NF * NF) return;
  int f = idx & 31, f2 = (idx >> 5) & 31, k = idx >> 10;
  tht[idx] = theta[(k * NF + f) * NF + f2];
}

// ==== cheb path: in-place softmax, on-the-fly A, full-batch-group launches ====

__global__ __launch_bounds__(256) void k_smax_ip(float* __restrict__ s1t,
                                                 float* __restrict__ sd) {
  const int n = blockIdx.x, b = blockIdx.y, tid = threadIdx.x;
  float* S = s1t + ((size_t)b * NN + n) * NN;
  __shared__ float red[256];
  float mx = -1e30f;
  for (int i = tid; i < NN; i += 256) mx = fmaxf(mx, S[i]);
  red[tid] = mx;
  __syncthreads();
  for (int s = 128; s > 0; s >>= 1) {
    if (tid < s) red[tid] = fmaxf(red[tid], red[tid + s]);
    __syncthreads();
  }
  mx = red[0];
  __syncthreads();
  float sum = 0.f;
  for (int i = tid; i < NN; i += 256) sum += __expf(S[i] - mx);
  red[tid] = sum;
  __syncthreads();
  for (int s = 128; s > 0; s >>= 1) {
    if (tid < s) red[tid] += red[tid + s];
    __syncthreads();
  }
  float inv = 1.f / red[0];
  for (int i = tid; i < NN; i += 256) {
    float v = __expf(S[i] - mx) * inv;
    S[i] = v;
    if (i == n) sd[(size_t)b * NN + n] = v;
  }
}

__global__ __launch_bounds__(256) void k_prepY2(const float* __restrict__ h,
                                                const float* __restrict__ tht, int T, int b0,
                                                unsigned short* __restrict__ Bb,
                                                float* __restrict__ Y0) {
  const int t = blockIdx.x, bl = blockIdx.y, b = b0 + bl;
  const int NFT = NF * T;
  const int tid = threadIdx.x;
  __shared__ float hs[NF * NN];  // [f][m]
  for (int l = tid; l < NF * NN; l += 256) {
    int m = l % NN, f = l / NN;
    hs[l] = h[((size_t)(b * NF + f) * NN + m) * T + t];
  }
  __syncthreads();
  const int lane = tid & 63;
  const int w = tid >> 6;
  for (int m = lane; m < 512; m += 64) {
    float hv[NF];
    const bool valid = m < NN;
#pragma unroll
    for (int f = 0; f < NF; f++) hv[f] = valid ? hs[f * NN + m] : 0.f;
    for (int f2q = 0; f2q < 8; f2q++) {
      const int f2 = f2q * 4 + w;
      float a0 = 0.f, a1 = 0.f, a2 = 0.f;
#pragma unroll
      for (int fq = 0; fq < 8; fq++) {
        float4 t0 = *(const float4*)&tht[(0 * NF + f2) * NF + fq * 4];
        float4 t1 = *(const float4*)&tht[(1 * NF + f2) * NF + fq * 4];
        float4 t2 = *(const float4*)&tht[(2 * NF + f2) * NF + fq * 4];
        a0 += hv[fq * 4 + 0] * t0.x + hv[fq * 4 + 1] * t0.y + hv[fq * 4 + 2] * t0.z + hv[fq * 4 + 3] * t0.w;
        a1 += hv[fq * 4 + 0] * t1.x + hv[fq * 4 + 1] * t1.y + hv[fq * 4 + 2] * t1.z + hv[fq * 4 + 3] * t1.w;
        a2 += hv[fq * 4 + 0] * t2.x + hv[fq * 4 + 1] * t2.y + hv[fq * 4 + 2] * t2.z + hv[fq * 4 + 3] * t2.w;
      }
      const int c = t * NF + f2;
      unsigned short* Bhi = Bb + (size_t)bl * NFT * 2048 + (size_t)c * 1024;
      unsigned short* Blo = Bhi + (size_t)NFT * 1024;
      if (valid) Y0[((size_t)bl * NFT + c) * NN + m] = a0;
      unsigned short h1 = bf16rne(a1);
      Bhi[m] = h1;
      Blo[m] = bf16rne(a1 - bfval(h1));
      unsigned short h2 = bf16rne(a2);
      Bhi[512 + m] = h2;
      Blo[512 + m] = bf16rne(a2 - bfval(h2));
    }
  }
}

__global__ __launch_bounds__(256) void k_cheb_mfma2(
    const unsigned short* __restrict__ Bb, const float* __restrict__ probs,
    const float* __restrict__ ct, const float* __restrict__ Y0,
    const float* __restrict__ sd, int b0, int NFT, float* __restrict__ outX) {
  const int bl = blockIdx.z, b = b0 + bl;
  const int n0 = blockIdx.y * 128;
  const int c0 = blockIdx.x * 128;
  const int tid = threadIdx.x, lane = tid & 63;
  const int wm = (tid >> 7) & 1, wn = (tid >> 6) & 1;
  __shared__ char lds[65536];  // 2 x 32KB: Ahi 8K | Alo 8K | Bhi 8K | Blo 8K
  const int ar = tid >> 1, ahf = tid & 1;          // A: row 0..127, 16-el half
  const int aw0 = ar * 64 + ((((ahf << 1) | 0) ^ (ar & 3)) << 4);
  const int aw1 = ar * 64 + ((((ahf << 1) | 1) ^ (ar & 3)) << 4);
  const int br = tid >> 1, bp = tid & 1;           // B: row 0..127, plane hi/lo
  int brr = c0 + br;
  if (brr >= NFT) brr = 0;                         // clamp: lands in write-masked cols
  const unsigned short* gB = Bb + (size_t)bl * NFT * 2048 + (size_t)bp * NFT * 1024
                                + (size_t)brr * 1024;
  int bw[4];
#pragma unroll
  for (int sl = 0; sl < 4; sl++) bw[sl] = (2 + bp) * 8192 + br * 64 + ((sl ^ (br & 3)) << 4);
  const float* pRow = probs + ((size_t)b * NN + (n0 + ar)) * NN;
  const size_t ctRow = (size_t)(n0 + ar) * NN;
  const int off16 = ((lane >> 4) ^ (lane & 3)) << 4;
  int rA[4], rB[4];
#pragma unroll
  for (int m = 0; m < 4; m++) rA[m] = (wm * 64 + m * 16 + (lane & 15)) * 64 + off16;
#pragma unroll
  for (int j = 0; j < 4; j++) rB[j] = (wn * 64 + j * 16 + (lane & 15)) * 64 + off16 + 16384;
  f32x4 acc[4][4] = {};
  float4 pv[4], cv[4], bv[4];
  auto loadK = [&](int kc) {
    const int pl = kc >> 4;
    const int mb = (kc & 15) * 32 + ahf * 16;
    const float* pp = pRow + mb;
    const float* cp = ct + (size_t)(pl + 1) * (NN * NN) + ctRow + mb;
#pragma unroll
    for (int q = 0; q < 4; q++) {
      pv[q] = *(const float4*)(pp + q * 4);
      cv[q] = *(const float4*)(cp + q * 4);
    }
    const unsigned short* bb = gB + kc * 32;
#pragma unroll
    for (int q = 0; q < 4; q++) bv[q] = *(const float4*)(bb + q * 8);
  };
  auto stage = [&](char* base) {
#pragma unroll
    for (int sl = 0; sl < 4; sl++) *(float4*)(base + bw[sl]) = bv[sl];
    float a[16];
#pragma unroll
    for (int q = 0; q < 4; q++) {
      a[q * 4 + 0] = pv[q].x * cv[q].x;
      a[q * 4 + 1] = pv[q].y * cv[q].y;
      a[q * 4 + 2] = pv[q].z * cv[q].z;
      a[q * 4 + 3] = pv[q].w * cv[q].w;
    }
    unsigned int hw[8], lw[8];
#pragma unroll
    for (int q = 0; q < 8; q++) {
      unsigned short h0 = bf16rne(a[q * 2]), h1 = bf16rne(a[q * 2 + 1]);
      hw[q] = (unsigned int)h0 | ((unsigned int)h1 << 16);
      unsigned short l0 = bf16rne(a[q * 2] - bfval(h0));
      unsigned short l1 = bf16rne(a[q * 2 + 1] - bfval(h1));
      lw[q] = (unsigned int)l0 | ((unsigned int)l1 << 16);
    }
    *(uint4*)(base + aw0) = make_uint4(hw[0], hw[1], hw[2], hw[3]);
    *(uint4*)(base + aw1) = make_uint4(hw[4], hw[5], hw[6], hw[7]);
    *(uint4*)(base + 8192 + aw0) = make_uint4(lw[0], lw[1], lw[2], lw[3]);
    *(uint4*)(base + 8192 + aw1) = make_uint4(lw[4], lw[5], lw[6], lw[7]);
  };
  loadK(0);
  stage(lds);
  __syncthreads();
  for (int kc = 0; kc < 32; kc++) {
    char* cur = lds + ((kc & 1) << 15);
    if (kc < 31) loadK(kc + 1);
    bf16x8 ah[4], al[4], bh[4], blr[4];
#pragma unroll
    for (int m = 0; m < 4; m++) {
      ah[m] = *(const bf16x8*)(cur + rA[m]);
      al[m] = *(const bf16x8*)(cur + rA[m] + 8192);
    }
#pragma unroll
    for (int j = 0; j < 4; j++) {
      bh[j] = *(const bf16x8*)(cur + rB[j]);
      blr[j] = *(const bf16x8*)(cur + rB[j] + 8192);
    }
#pragma unroll
    for (int m = 0; m < 4; m++)
#pragma unroll
      for (int j = 0; j < 4; j++) {
        acc[m][j] = __builtin_amdgcn_mfma_f32_16x16x32_bf16(ah[m], bh[j], acc[m][j], 0, 0, 0);
        acc[m][j] = __builtin_amdgcn_mfma_f32_16x16x32_bf16(al[m], bh[j], acc[m][j], 0, 0, 0);
        acc[m][j] = __builtin_amdgcn_mfma_f32_16x16x32_bf16(ah[m], blr[j], acc[m][j], 0, 0, 0);
      }
    if (kc < 31) stage(lds + (((kc & 1) ^ 1) << 15));
    __syncthreads();
  }
#pragma unroll
  for (int m = 0; m < 4; m++) {
    const int nb = n0 + wm * 64 + m * 16 + (lane >> 4) * 4;
#pragma unroll
    for (int j = 0; j < 4; j++) {
      const int c = c0 + wn * 64 + j * 16 + (lane & 15);
      if (c < NFT) {
        const float* Yc = Y0 + ((size_t)bl * NFT + c) * NN;
#pragma unroll
        for (int rg = 0; rg < 4; rg++) {
          const int n = nb + rg;
          if (n < NN) {
            float v = acc[m][j][rg] + sd[(size_t)b * NN + n] * Yc[n];
            outX[((size_t)b * NN + n) * NFT + c] = fmaxf(v, 0.f);
          }
        }
      }
    }
  }
}

// ---- layer norm over (C,N,T) per sample; one block per b ----
__global__ __launch_bounds__(256) void k_ln_stat(const float* x, float* stat, int M) {
  int b = blockIdx.x;
  const float* xp = x + (size_t)b * M;
  float s1 = 0.f, s2 = 0.f;
  for (int i = threadIdx.x; i < M; i += 256) {
    float v = xp[i]; s1 += v; s2 += v * v;
  }
  __shared__ float r1[256], r2[256];
  int tid = threadIdx.x;
  r1[tid] = s1; r2[tid] = s2;
  __syncthreads();
  for (int s = 128; s > 0; s >>= 1) {
    if (tid < s) { r1[tid] += r1[tid + s]; r2[tid] += r2[tid + s]; }
    __syncthreads();
  }
  if (tid == 0) {
    float mean = r1[0] / M;
    float var = r2[0] / M - mean * mean;
    stat[b * 2] = mean;
    stat[b * 2 + 1] = rsqrtf(var + 1e-5f);
  }
}
__global__ void k_ln_norm(const float* x, const float* stat, const float* wn, const float* bn,
                          float* out, int M) {
  int total = NB * M;
  int idx = blockIdx.x * 256 + threadIdx.x;
  if (idx >= total) return;
  int b = idx / M;
  int i = idx % M;
  float y = (x[idx] - stat[b * 2]) * stat[b * 2 + 1];
  out[idx] = y * wn[i] + bn[i];
}

// ---- final head ----
__global__ void k_fin1(const float* h, const float* w, const float* bias, const float* skip,
                       float* out) {
  int total = NB * 64 * NN;
  int idx = blockIdx.x * 256 + threadIdx.x;
  if (idx >= total) return;
  int n = idx % NN;
  int c = (idx / NN) % 64;
  int b = idx / (NN * 64);
  float v = bias[c];
  for (int ci = 0; ci < 32; ci++) v += w[c * 32 + ci] * h[(b * NF + ci) * NN + n];
  v += skip[((size_t)(b * 64 + c) * NN + n) * 7 + 6];
  out[idx] = fmaxf(v, 0.f);
}
__global__ void k_fin2(const float* in, const float* w, const float* bias, float* out) {
  int total = NB * 128 * NN;
  int idx = blockIdx.x * 256 + threadIdx.x;
  if (idx >= total) return;
  int n = idx % NN;
  int c = (idx / NN) % 128;
  int b = idx / (NN * 128);
  float v = bias[c];
  for (int ci = 0; ci < 64; ci++) v += w[c * 64 + ci] * in[(b * 64 + ci) * NN + n];
  out[idx] = fmaxf(v, 0.f);
}
__global__ void k_fin3(const float* in, const float* w, const float* bias, float* out) {
  int total = NB * 12 * NN;
  int idx = blockIdx.x * 256 + threadIdx.x;
  if (idx >= total) return;
  int n = idx % NN;
  int c = (idx / NN) % 12;
  int b = idx / (NN * 12);
  float v = bias[c];
  for (int ci = 0; ci < 128; ci++) v += w[c * 128 + ci] * in[(b * 128 + ci) * NN + n];
  out[idx] = v;
}

#define G1(tot) dim3((unsigned)(((tot) + 255) / 256)), dim3(256), 0, stream

extern "C" void kernel_launch(void* const* d_in, const int* in_sizes, int n_in,
                              void* d_out, int out_size, void* d_ws, size_t ws_size,
                              hipStream_t stream) {
  (void)in_sizes; (void)n_in; (void)out_size; (void)ws_size;
  auto I = [&](int i) { return (const float*)d_in[i]; };
  float* W = (float*)d_ws;
  size_t off = 0;
  auto alloc = [&](size_t nel) { float* p = W + off; off += nel; return p; };

  float* bufA  = alloc(9728000);   // h / residual [B,32,N,19max]
  float* bufB  = alloc(9728000);   // h after fc1; later cheb output (t-major, in place)
  float* bufC  = alloc(9728000);   // x_tat -> s1T -> probs (in-place softmax)
  float* bufSK = alloc(7168000);   // skip [B,64,N,7]
  float* skip0 = alloc(1024000);   // skip [B,64,N,1]; dead after layer-0 skipconv
  float* P1    = alloc(9728000);   // s0; dead after k_gemm_vs (within each layer)
  float* CT    = alloc(750000);    // chebT
  float* VST   = alloc(250000);    // vs transposed (per layer)
  float* TL1   = alloc(19456);
  float* TLH   = alloc(304000);
  float* TRH   = alloc(304000);
  float* TE    = alloc(11552);
  float* TE0   = alloc(11552);     // e0 intermediate
  float* SL1   = alloc(512000);
  float* SLH   = alloc(304000);
  float* SRH   = alloc(304000);
  float* ACC   = alloc(64);
  float* SD    = alloc(16000);     // sd[b][n] = p[b,n,n]
  float* THT   = alloc(3072);      // thetaT[k][f2][f]
  // NOTE: total footprint kept EXACTLY at the R5-passing level (199.57 MB). R6 appended
  // WP at the end (+123 KB) and overflowed ws_size -> corrupted adjacent input memory on
  // calls >= 2 (first call passed, later calls stably wrong). WP now lives in the free
  // tail of the cheb staging region (see below) — zero footprint growth.

  // cheb staging: reuse skip0+P1 (contiguous 10,752,000 floats, dead at cheb time).
  constexpr int GB = 11;
  float* STG = skip0;
  unsigned short* Bb = (unsigned short*)STG;   // [bl][2][NFT][1024] bf16 (ends 6,848,512)
  float* Y0f = STG + 6848512;                  // [bl][NFT][500] fp32 (ends 10,192,512)
  // free tail of STG: [10,192,512 .. 10,752,000) — 559,488 floats; WP needs 30,720.
  // Written once per call by k_packW (before prepY2 of layer 0? no — packed at call
  // start, read by every k_gtu_mfma). Verified untouched by Bb/Y0f/s0/F1/F2.
  unsigned short* WP = (unsigned short*)(Y0f + 3344000);

  float* P2 = bufC;                // s1T/probs live in bufC through the cheb GEMM
  float* F1 = P1;                  // [B,64,N] final head, after staging is dead
  float* F2 = P1 + 1024000;        // [B,128,N]

  k_start<<<G1(NB * NF * NN * 19)>>>(I(0), I(1), I(2), bufA);
  k_skip0<<<G1(NB * 64 * NN)>>>(I(0), I(3), I(4), skip0);
  k_chebT<<<G1(3 * NN * NN)>>>(I(59), CT);
  k_thetaT<<<G1(3 * NF * NF)>>>(I(60), THT);
  k_packW<<<G1(15 * 2048)>>>(I(5), I(7), I(9), WP);

  dim3 ggt((NN + 7) / 8, NB), bgt(256);
  auto gtufc = [&](int Ti, const float* hin, const float* fw, const float* fb, float* o) {
    if (Ti == 19)
      k_gtu_mfma<19, 19, false><<<ggt, bgt, 0, stream>>>(hin, WP, I(6), I(8), I(10), fw, fb, nullptr, o);
    else if (Ti == 13)
      k_gtu_mfma<13, 13, false><<<ggt, bgt, 0, stream>>>(hin, WP, I(6), I(8), I(10), fw, fb, nullptr, o);
    else
      k_gtu_mfma<7, 7, false><<<ggt, bgt, 0, stream>>>(hin, WP, I(6), I(8), I(10), fw, fb, nullptr, o);
  };
  auto gtufcx = [&](int Ti, const float* hin, const float* fw, const float* fb,
                    const float* res, float* o) {
    if (Ti == 19)
      k_gtu_mfma<19, 13, true><<<ggt, bgt, 0, stream>>>(hin, WP, I(6), I(8), I(10), fw, fb, res, o);
    else if (Ti == 13)
      k_gtu_mfma<13, 7, true><<<ggt, bgt, 0, stream>>>(hin, WP, I(6), I(8), I(10), fw, fb, res, o);
    else
      k_gtu_mfma<7, 1, true><<<ggt, bgt, 0, stream>>>(hin, WP, I(6), I(8), I(10), fw, fb, res, o);
  };

  const int Tin[3] = {19, 13, 7};
  for (int i = 0; i < 3; i++) {
    int Ti = Tin[i];
    // gated TCN + fc1 + relu-add : bufA -> bufB
    gtufc(Ti, bufA, I(11 + 2 * i), I(12 + 2 * i), bufB);
    // skip conv
    if (i == 0)
      k_skipconv_t<19, 13><<<ggt, bgt, 0, stream>>>(bufB, I(23), I(24), skip0, 1, bufSK);
    else if (i == 1)
      k_skipconv_t<13, 7><<<ggt, bgt, 0, stream>>>(bufB, I(25), I(26), bufSK, 7, bufSK);
    else
      k_skipconv_t<7, 1><<<ggt, bgt, 0, stream>>>(bufB, I(27), I(28), bufSK, 7, bufSK);
    // temporal attention
    int ba = 29 + i * 10;
    k_zero<<<G1(NB * Ti * NF)>>>(TL1, NB * Ti * NF);
    k_ta_lhs1b<<<dim3(20, NB), dim3(256), 0, stream>>>(bufB, I(ba + 0), TL1, Ti);
    k_ta_lhs<<<G1(NB * Ti * NN)>>>(TL1, I(ba + 1), TLH, Ti);
    k_ta_rhs<<<G1(NB * NN * Ti)>>>(bufB, I(ba + 2), TRH, Ti);
    k_ta_e0<<<dim3(Ti, NB), dim3(256), 0, stream>>>(TLH, TRH, I(ba + 3), TE0, Ti);
    k_ta_att2<<<dim3(NB), dim3(256), 0, stream>>>(TE0, I(ba + 4), TE, Ti);
    k_xtat<<<G1(NB * NF * NN * Ti)>>>(TE, bufB, bufC, Ti);  // x_tat into bufC
    // spatial attention
    k_sa_lhs1<<<G1(NB * NN * NF)>>>(bufC, I(ba + 5), SL1, Ti);
    k_sa_lhs<<<G1(NB * NN * Ti)>>>(SL1, I(ba + 6), SLH, Ti);
    k_sa_rhs<<<G1(NB * Ti * NN)>>>(bufC, I(ba + 7), SRH, Ti);
    k_sa_prod<<<G1(NB * NN * NN)>>>(SLH, SRH, I(ba + 8), P1, Ti);  // x_tat consumed
    k_transpose<<<dim3(16, 16), dim3(256), 0, stream>>>(I(ba + 9), VST);
    {
      dim3 gg((NN + 127) / 128, 8, NB);
      k_gemm_vs<<<gg, dim3(256), 0, stream>>>(VST, P1, P2);  // s1T into bufC; P1 free
    }
    // ==== cheb conv via bf16x3 MFMA ====
    int NFT = NF * Ti;
    k_smax_ip<<<dim3(NN, NB), dim3(256), 0, stream>>>(P2, SD);  // probs in place in bufC
    for (int b0 = 0; b0 < NB; b0 += GB) {
      int gsz = (NB - b0 < GB) ? (NB - b0) : GB;
      k_prepY2<<<dim3(Ti, gsz), dim3(256), 0, stream>>>(bufB, THT, Ti, b0, Bb, Y0f);
      dim3 gm((NFT + 127) / 128, 4, gsz);
      k_cheb_mfma2<<<gm, dim3(256), 0, stream>>>(Bb, P2, CT, Y0f, SD, b0, NFT, bufB);
    }
    // second gated TCN (t-major input) + fc2 + relu-add + residual : bufB (+bufA) -> bufC
    gtufcx(Ti, bufB, I(17 + 2 * i), I(18 + 2 * i), bufA, bufC);
    // layer norm: bufC -> bufA
    int M = NF * NN * (Ti == 19 ? 13 : Ti == 13 ? 7 : 1);
    k_ln_stat<<<dim3(NB), dim3(256), 0, stream>>>(bufC, ACC, M);
    k_ln_norm<<<G1(NB * M)>>>(bufC, ACC, I(61 + 2 * i), I(62 + 2 * i), bufA, M);
  }
  // final head
  k_fin1<<<G1(NB * 64 * NN)>>>(bufA, I(67), I(68), bufSK, F1);
  k_fin2<<<G1(NB * 128 * NN)>>>(F1, I(69), I(70), F2);
  k_fin3<<<G1(NB * 12 * NN)>>>(F2, I(71), I(72), (float*)d_out);
}